// Round 3
// baseline (3047.581 us; speedup 1.0000x reference)
//
#include <hip/hip_runtime.h>

// ---------------- types / helpers ----------------
typedef __attribute__((ext_vector_type(8))) short short8;
typedef __attribute__((ext_vector_type(4))) short short4v;
typedef __attribute__((ext_vector_type(4))) float float4v;
typedef __bf16 bf16x8 __attribute__((ext_vector_type(8)));

__device__ __forceinline__ float4v mfma16(short8 a, short8 b, float4v c) {
  return __builtin_amdgcn_mfma_f32_16x16x32_bf16(
      __builtin_bit_cast(bf16x8, a), __builtin_bit_cast(bf16x8, b), c, 0, 0, 0);
}

// MFMA with B operand pinned to the AGPR file (keeps 400-reg Whh resident).
__device__ __forceinline__ void mfma_av(float4v& c, short8 a, short8 b) {
  asm("v_mfma_f32_16x16x32_bf16 %0, %1, %2, %0" : "+v"(c) : "v"(a), "a"(b));
}

__device__ __forceinline__ short8 cat44(short4v a, short4v b) {
  short8 r;
  r[0]=a[0]; r[1]=a[1]; r[2]=a[2]; r[3]=a[3];
  r[4]=b[0]; r[5]=b[1]; r[6]=b[2]; r[7]=b[3];
  return r;
}

__device__ __forceinline__ unsigned short bf16_rne(float x) {
  unsigned u = __builtin_bit_cast(unsigned, x);
  u += 0x7fffu + ((u >> 16) & 1u);
  return (unsigned short)(u >> 16);
}
__device__ __forceinline__ float bf16_f(unsigned short h) {
  return __builtin_bit_cast(float, ((unsigned)h) << 16);
}
__device__ __forceinline__ void split_bf16(float x, unsigned short& hi, unsigned short& lo) {
  hi = bf16_rne(x);
  lo = bf16_rne(x - bf16_f(hi));
}

#define KLOG2E 1.442695041f
__device__ __forceinline__ float fast_sig(float x) {
  float z = __builtin_amdgcn_exp2f(-KLOG2E * x);
  return __builtin_amdgcn_rcpf(1.f + z);
}
__device__ __forceinline__ float fast_tanh(float x) {
  float z = __builtin_amdgcn_exp2f(2.f * KLOG2E * x);
  return 1.f - 2.f * __builtin_amdgcn_rcpf(1.f + z);
}

// sizes
// B=16 L=96 H=150 4H=600(pad 640) EMB=150(pad 160) 2H=300(pad 320)
// rows indexed row = t*16 + b

// ---------------- prep: weight fragment layouts + bf16 hi/lo splits ----------------
// fragment slot formula (same for A and B operands):
//   k(lane,e) = 32*kc + 16*(e>>2) + 4*(lane>>4) + (e&3)
__global__ void prep_kernel(
    const float* __restrict__ Wih0,   // [2][600][150]
    const float* __restrict__ WihR,   // [3][2][600][300]
    const float* __restrict__ Whh,    // [4][2][600][150]
    const float* __restrict__ bih,    // [4][2][600]
    const float* __restrict__ bhh,    // [4][2][600]
    const float* __restrict__ w1m,    // [100][600]
    const float* __restrict__ b1v,    // [100]
    unsigned short* __restrict__ whh_hi, unsigned short* __restrict__ whh_lo,
    unsigned short* __restrict__ wih_hi, unsigned short* __restrict__ wih_lo,
    unsigned short* __restrict__ wpr_hi, unsigned short* __restrict__ wpr_lo,
    float* __restrict__ bsum, float* __restrict__ b1cat)
{
  const int N_whh  = 8 * 40 * 5 * 512;   // 819200
  const int N_wih0 = 2 * 40 * 5 * 512;   // 204800
  const int N_wihr = 6 * 40 * 10 * 512;  // 1228800
  const int N_wpr  = 16 * 10 * 512;      // 81920
  const int N_bs   = 8 * 640;            // 5120
  const int total  = N_whh + N_wih0 + N_wihr + N_wpr + N_bs + 256;
  for (int i = blockIdx.x * blockDim.x + threadIdx.x; i < total;
       i += gridDim.x * blockDim.x) {
    int idx = i;
    if (idx < N_whh) {
      int e = idx & 7, lane = (idx >> 3) & 63, r = idx >> 9;
      int kc = r % 5; r /= 5; int nt = r % 40; int ld = r / 40;
      int g = 16 * nt + (lane & 15);
      int j = 32 * kc + 16 * (e >> 2) + 4 * (lane >> 4) + (e & 3);
      float v = (g < 600 && j < 150) ? Whh[((size_t)ld * 600 + g) * 150 + j] : 0.f;
      unsigned short h, l; split_bf16(v, h, l);
      whh_hi[idx] = h; whh_lo[idx] = l;
      continue;
    }
    idx -= N_whh;
    if (idx < N_wih0) {
      int e = idx & 7, lane = (idx >> 3) & 63, r = idx >> 9;
      int kc = r % 5; r /= 5; int nt = r % 40; int dir = r / 40;
      int g = 16 * nt + (lane & 15);
      int j = 32 * kc + 16 * (e >> 2) + 4 * (lane >> 4) + (e & 3);
      float v = (g < 600 && j < 150) ? Wih0[((size_t)dir * 600 + g) * 150 + j] : 0.f;
      unsigned short h, l; split_bf16(v, h, l);
      wih_hi[idx] = h; wih_lo[idx] = l;
      continue;
    }
    idx -= N_wih0;
    if (idx < N_wihr) {
      int e = idx & 7, lane = (idx >> 3) & 63, r = idx >> 9;
      int kc = r % 10; r /= 10; int nt = r % 40; int ld = r / 40;
      int g = 16 * nt + (lane & 15);
      int j = 32 * kc + 16 * (e >> 2) + 4 * (lane >> 4) + (e & 3);
      float v = (g < 600 && j < 300) ? WihR[((size_t)ld * 600 + g) * 300 + j] : 0.f;
      unsigned short h, l; split_bf16(v, h, l);
      wih_hi[N_wih0 + idx] = h; wih_lo[N_wih0 + idx] = l;
      continue;
    }
    idx -= N_wihr;
    if (idx < N_wpr) {
      int e = idx & 7, lane = (idx >> 3) & 63, r = idx >> 9;
      int kc = r % 10; int nt = r / 10;
      int ko = 16 * nt + (lane & 15);
      int j = 32 * kc + 16 * (e >> 2) + 4 * (lane >> 4) + (e & 3);
      float v = 0.f;
      if (j < 300) {
        if (ko < 100) v = w1m[(size_t)ko * 600 + j];
        else if (ko < 200) v = w1m[(size_t)(ko - 100) * 600 + 300 + j];
      }
      unsigned short h, l; split_bf16(v, h, l);
      wpr_hi[idx] = h; wpr_lo[idx] = l;
      continue;
    }
    idx -= N_wpr;
    if (idx < N_bs) {
      int ld = idx / 640, g = idx - 640 * ld;
      bsum[idx] = (g < 600) ? bih[ld * 600 + g] + bhh[ld * 600 + g] : 0.f;
      continue;
    }
    idx -= N_bs;
    b1cat[idx] = (idx < 100) ? b1v[idx] : ((idx < 200) ? b1v[idx - 100] : 0.f);
  }
}

// ---------------- embedding gather ----------------
__global__ void embed_kernel(const int* __restrict__ widx, const int* __restrict__ pidx,
    const float* __restrict__ wemb, const float* __restrict__ temb,
    unsigned short* __restrict__ xa_hi, unsigned short* __restrict__ xa_lo,
    unsigned short* __restrict__ xb_hi, unsigned short* __restrict__ xb_lo)
{
  int row = blockIdx.x;       // t*16 + b
  int j = threadIdx.x;        // 0..319
  int b = row & 15, t = row >> 4;
  float v = 0.f;
  if (j < 100) v = wemb[(size_t)widx[b * 96 + t] * 100 + j];
  else if (j < 150) v = temb[(size_t)pidx[b * 96 + t] * 50 + (j - 100)];
  unsigned short h, l; split_bf16(v, h, l);
  size_t o = (size_t)row * 320 + j;
  xa_hi[o] = h; xa_lo[o] = l;
  if (j >= 300) { xb_hi[o] = 0; xb_lo[o] = 0; }
}

// ---------------- pre-GEMM: pre[d][t][b][g] = x @ Wih^T + b_ih + b_hh ----------------
template <int KC>
__global__ __launch_bounds__(512) void pregemm_kernel(
    const unsigned short* __restrict__ x_hi, const unsigned short* __restrict__ x_lo,
    const unsigned short* __restrict__ wih_h, const unsigned short* __restrict__ wih_l,
    const float* __restrict__ bsum_l,
    float* __restrict__ pre)            // [2][96][16][640]
{
  const int t = blockIdx.x, dir = blockIdx.y;
  const int tid = threadIdx.x, wv = tid >> 6, lane = tid & 63;
  const int lrow = lane & 15, lgrp = lane >> 4;
  const unsigned short* wh = wih_h + (size_t)dir * 40 * KC * 512;
  const unsigned short* wl = wih_l + (size_t)dir * 40 * KC * 512;
  float4v acc[5];
#pragma unroll
  for (int tt = 0; tt < 5; ++tt) acc[tt] = (float4v){0.f, 0.f, 0.f, 0.f};
  const size_t arow = ((size_t)t * 16 + lrow) * 320;
#pragma unroll
  for (int kc = 0; kc < KC; ++kc) {
    int co = 32 * kc + 4 * lgrp;
    short8 ah = cat44(*(const short4v*)(x_hi + arow + co),
                      *(const short4v*)(x_hi + arow + co + 16));
    short8 al = cat44(*(const short4v*)(x_lo + arow + co),
                      *(const short4v*)(x_lo + arow + co + 16));
#pragma unroll
    for (int tt = 0; tt < 5; ++tt) {
      int nt = 5 * wv + tt;
      const size_t wo = ((size_t)(nt * KC + kc) * 64 + lane) * 8;
      short8 bh = *(const short8*)(wh + wo);
      short8 bl = *(const short8*)(wl + wo);
      acc[tt] = mfma16(ah, bh, acc[tt]);
      acc[tt] = mfma16(al, bh, acc[tt]);
      acc[tt] = mfma16(ah, bl, acc[tt]);
    }
  }
  float* po = pre + ((size_t)dir * 96 + t) * 16 * 640;
  const float* bs = bsum_l + dir * 640;
#pragma unroll
  for (int tt = 0; tt < 5; ++tt) {
    int g = 16 * (5 * wv + tt) + lrow;
    float bv = bs[g];
#pragma unroll
    for (int jj = 0; jj < 4; ++jj)
      po[(size_t)(4 * lgrp + jj) * 640 + g] = acc[tt][jj] + bv;
  }
}

// ---------------- sequential LSTM scan, one 4-wave block per direction ----------------
// 4 waves = 1 wave/SIMD -> 512-reg unified budget. Whh fragments (400 regs) are
// pinned to the AGPR file via inline-asm "a" operand constraints on the MFMA.
__global__ __launch_bounds__(256, 1) void scan_kernel(
    const float* __restrict__ pre,                 // [2][96][16][640]
    const unsigned short* __restrict__ whh_hi,
    const unsigned short* __restrict__ whh_lo,
    unsigned short* __restrict__ xo_hi, unsigned short* __restrict__ xo_lo, // [1536][320]
    int layer)
{
  const int dir = blockIdx.x;
  const int tid = threadIdx.x, wv = tid >> 6, lane = tid & 63;
  const int lrow = lane & 15, lgrp = lane >> 4;

  // h in MFMA A-fragment order: pos = b*168 + kc*32 + q*8 + e   (q = lane>>4)
  __shared__ __align__(16) unsigned short h_hi[16 * 168];
  __shared__ __align__(16) unsigned short h_lo[16 * 168];
  __shared__ float gA[16 * 644];   // raw pre-activation sums (incl. PRE via acc init)

  for (int i = tid; i < 16 * 168; i += 256) { h_hi[i] = 0; h_lo[i] = 0; }

  // Whh fragments: 10 N-tiles x 5 kc x {hi,lo} per wave -> AGPRs
  const unsigned short* bh_base = whh_hi + (size_t)(layer * 2 + dir) * 40 * 5 * 512;
  const unsigned short* bl_base = whh_lo + (size_t)(layer * 2 + dir) * 40 * 5 * 512;
  short8 Bh[10][5], Bl[10][5];
#pragma unroll
  for (int tt = 0; tt < 10; ++tt)
#pragma unroll
    for (int kc = 0; kc < 5; ++kc) {
      size_t o = ((size_t)((10 * wv + tt) * 5 + kc) * 64 + lane) * 8;
      Bh[tt][kc] = *(const short8*)(bh_base + o);
      Bl[tt][kc] = *(const short8*)(bl_base + o);
    }

  float cst[10];
#pragma unroll
  for (int ii = 0; ii < 10; ++ii) cst[ii] = 0.f;

  const float* preD = pre + (size_t)dir * 96 * 16 * 640;
  __syncthreads();

#pragma unroll 1
  for (int step = 0; step < 96; ++step) {
    const int t = dir ? (95 - step) : step;
    const float* pt = preD + (size_t)t * 16 * 640;

    // acc initialized from PRE (C-input carries x@Wih + biases)
    float4v acc[10];
#pragma unroll
    for (int tt = 0; tt < 10; ++tt) {
      int g = 16 * (10 * wv + tt) + lrow;
#pragma unroll
      for (int jj = 0; jj < 4; ++jj)
        acc[tt][jj] = pt[(size_t)(4 * lgrp + jj) * 640 + g];
    }

#pragma unroll
    for (int kc = 0; kc < 5; ++kc) {
      const int ao = lrow * 168 + kc * 32 + lgrp * 8;
      short8 ah = *(const short8*)(h_hi + ao);
      short8 al = *(const short8*)(h_lo + ao);
#pragma unroll
      for (int tt = 0; tt < 10; ++tt) {
        mfma_av(acc[tt], ah, Bh[tt][kc]);
        mfma_av(acc[tt], al, Bh[tt][kc]);
        mfma_av(acc[tt], ah, Bl[tt][kc]);
      }
    }

    // MFMA-D -> VALU-read hazard fence (inline asm hides MFMAs from the
    // hazard recognizer; 2x s_nop 7 covers the 4-pass XDL latency)
    __builtin_amdgcn_sched_barrier(0);
    asm volatile("s_nop 7\n\ts_nop 7");
    __builtin_amdgcn_sched_barrier(0);

    // raw pre-activations to LDS (nonlinearity deferred to state phase)
#pragma unroll
    for (int tt = 0; tt < 10; ++tt) {
      int g = 16 * (10 * wv + tt) + lrow;
#pragma unroll
      for (int jj = 0; jj < 4; ++jj)
        gA[(4 * lgrp + jj) * 644 + g] = acc[tt][jj];
    }
    __syncthreads();

    // state update: thread owns fixed (b,j) cells, c kept in registers
#pragma unroll
    for (int ii = 0; ii < 10; ++ii) {
      int e = tid + 256 * ii;
      if (e < 2400) {
        int b = e / 150;              // magic-mul
        int j = e - 150 * b;
        const float* gb = gA + b * 644 + j;
        float i_ = fast_sig(gb[0]);
        float f_ = fast_sig(gb[150]);
        float g_ = fast_tanh(gb[300]);
        float o_ = fast_sig(gb[450]);
        float c = f_ * cst[ii] + i_ * g_;
        cst[ii] = c;
        float h = o_ * fast_tanh(c);
        unsigned short hh, hl; split_bf16(h, hh, hl);
        int kc = j >> 5, w = j & 31;
        int off = b * 168 + kc * 32 + ((w >> 2) & 3) * 8 + (w >> 4) * 4 + (w & 3);
        h_hi[off] = hh; h_lo[off] = hl;
        size_t gout = ((size_t)t * 16 + b) * 320 + dir * 150 + j;
        xo_hi[gout] = hh; xo_lo[gout] = hl;
      }
    }
    __syncthreads();
  }
}

// ---------------- elementwise degree-4 polynomial ----------------
__global__ void poly_kernel(const unsigned short* __restrict__ xi_hi,
    const unsigned short* __restrict__ xi_lo,
    unsigned short* __restrict__ xo_hi, unsigned short* __restrict__ xo_lo,
    const float* __restrict__ w1, const float* __restrict__ w2,
    const float* __restrict__ w3, const float* __restrict__ w4)
{
  int i = blockIdx.x * 256 + threadIdx.x;
  if (i >= 1536 * 320) return;
  float x = bf16_f(xi_hi[i]) + bf16_f(xi_lo[i]);
  float p = x * (w1[0] + x * (w2[0] + x * (w3[0] + x * w4[0])));
  unsigned short h, l; split_bf16(p, h, l);
  xo_hi[i] = h; xo_lo[i] = l;
}

// ---------------- projection: AD[row][0:100]=A+b1, [100:200]=D ----------------
__global__ __launch_bounds__(512) void proj_kernel(
    const unsigned short* __restrict__ p_hi, const unsigned short* __restrict__ p_lo,
    const unsigned short* __restrict__ wpr_hi, const unsigned short* __restrict__ wpr_lo,
    const float* __restrict__ b1cat,
    float* __restrict__ AD)   // [1536][256]
{
  const int t = blockIdx.x;
  const int tid = threadIdx.x, wv = tid >> 6, lane = tid & 63;
  const int lrow = lane & 15, lgrp = lane >> 4;
  float4v acc[2] = {{0.f, 0.f, 0.f, 0.f}, {0.f, 0.f, 0.f, 0.f}};
  const size_t arow = ((size_t)t * 16 + lrow) * 320;
#pragma unroll
  for (int kc = 0; kc < 10; ++kc) {
    int co = 32 * kc + 4 * lgrp;
    short8 ah = cat44(*(const short4v*)(p_hi + arow + co),
                      *(const short4v*)(p_hi + arow + co + 16));
    short8 al = cat44(*(const short4v*)(p_lo + arow + co),
                      *(const short4v*)(p_lo + arow + co + 16));
#pragma unroll
    for (int tt = 0; tt < 2; ++tt) {
      int nt = 2 * wv + tt;
      size_t wo = ((size_t)(nt * 10 + kc) * 64 + lane) * 8;
      short8 bh = *(const short8*)(wpr_hi + wo);
      short8 bl = *(const short8*)(wpr_lo + wo);
      acc[tt] = mfma16(ah, bh, acc[tt]);
      acc[tt] = mfma16(al, bh, acc[tt]);
      acc[tt] = mfma16(ah, bl, acc[tt]);
    }
  }
#pragma unroll
  for (int tt = 0; tt < 2; ++tt) {
    int ko = 16 * (2 * wv + tt) + lrow;
    float bv = b1cat[ko];
#pragma unroll
    for (int jj = 0; jj < 4; ++jj)
      AD[((size_t)t * 16 + 4 * lgrp + jj) * 256 + ko] = acc[tt][jj] + bv;
  }
}

// ---------------- combine: out[lh][b][ld] = b2 + sum_k w2[k]*tanh(A+D) ----------------
__global__ __launch_bounds__(768) void combine_kernel(
    const float* __restrict__ AD, const float* __restrict__ w2v,
    const float* __restrict__ b2v, float* __restrict__ out)
{
  const int bb = blockIdx.x & 15, lt = blockIdx.x >> 4;
  const int tid = threadIdx.x;
  __shared__ float Dl[100 * 97];  // [k][ld], stride 97
  __shared__ float Al[100 * 9];   // [k][lh], stride 9
  __shared__ float w2s[100];
  for (int i = tid; i < 96 * 32; i += 768) {
    int ld = i >> 5, f4 = i & 31;
    if (f4 < 25) {
      float4v v = *(const float4v*)(AD + ((size_t)ld * 16 + bb) * 256 + 100 + 4 * f4);
      int k0 = 4 * f4;
      Dl[(k0 + 0) * 97 + ld] = v[0];
      Dl[(k0 + 1) * 97 + ld] = v[1];
      Dl[(k0 + 2) * 97 + ld] = v[2];
      Dl[(k0 + 3) * 97 + ld] = v[3];
    }
  }
  for (int i = tid; i < 8 * 32; i += 768) {
    int lh = i >> 5, f4 = i & 31;
    if (f4 < 25) {
      int lseq = lt * 8 + lh;
      float4v v = *(const float4v*)(AD + ((size_t)lseq * 16 + bb) * 256 + 4 * f4);
      int k0 = 4 * f4;
      Al[(k0 + 0) * 9 + lh] = v[0];
      Al[(k0 + 1) * 9 + lh] = v[1];
      Al[(k0 + 2) * 9 + lh] = v[2];
      Al[(k0 + 3) * 9 + lh] = v[3];
    }
  }
  if (tid < 100) w2s[tid] = w2v[tid];
  __syncthreads();
  int lh = tid / 96, ld = tid - 96 * lh;
  float s = 0.f;
#pragma unroll 4
  for (int k = 0; k < 100; ++k) {
    float x = Al[k * 9 + lh] + Dl[k * 97 + ld];
    s += w2s[k] * fast_tanh(x);
  }
  out[((size_t)(lt * 8 + lh) * 16 + bb) * 96 + ld] = s + b2v[0];
}

// ---------------- host ----------------
extern "C" void kernel_launch(void* const* d_in, const int* in_sizes, int n_in,
                              void* d_out, int out_size, void* d_ws, size_t ws_size,
                              hipStream_t stream)
{
  const int*   widx = (const int*)d_in[0];
  const int*   pidx = (const int*)d_in[1];
  const float* wemb = (const float*)d_in[3];
  const float* temb = (const float*)d_in[4];
  const float* Wih0 = (const float*)d_in[5];
  const float* WihR = (const float*)d_in[6];
  const float* Whh  = (const float*)d_in[7];
  const float* bih  = (const float*)d_in[8];
  const float* bhh  = (const float*)d_in[9];
  const float* w1   = (const float*)d_in[10];
  const float* w2   = (const float*)d_in[11];
  const float* w3   = (const float*)d_in[12];
  const float* w4   = (const float*)d_in[13];
  const float* w1m  = (const float*)d_in[14];
  const float* b1v  = (const float*)d_in[15];
  const float* w2m  = (const float*)d_in[16];
  const float* b2v  = (const float*)d_in[17];
  float* out = (float*)d_out;

  char* ws = (char*)d_ws;
  size_t off = 0;
  auto alloc = [&](size_t bytes) -> char* {
    char* p = ws + off;
    off = (off + bytes + 255) & ~(size_t)255;
    return p;
  };
  unsigned short* WHH_HI = (unsigned short*)alloc(819200ull * 2);
  unsigned short* WHH_LO = (unsigned short*)alloc(819200ull * 2);
  unsigned short* WIH_HI = (unsigned short*)alloc(1433600ull * 2);
  unsigned short* WIH_LO = (unsigned short*)alloc(1433600ull * 2);
  unsigned short* WPR_HI = (unsigned short*)alloc(81920ull * 2);
  unsigned short* WPR_LO = (unsigned short*)alloc(81920ull * 2);
  float* BSUM = (float*)alloc(5120ull * 4);
  float* B1C  = (float*)alloc(256ull * 4);
  unsigned short* XA_HI = (unsigned short*)alloc(491520ull * 2);
  unsigned short* XA_LO = (unsigned short*)alloc(491520ull * 2);
  unsigned short* XB_HI = (unsigned short*)alloc(491520ull * 2);
  unsigned short* XB_LO = (unsigned short*)alloc(491520ull * 2);
  float* PRE = (float*)alloc(1966080ull * 4);
  float* AD  = (float*)alloc(1536ull * 256 * 4);

  prep_kernel<<<512, 256, 0, stream>>>(Wih0, WihR, Whh, bih, bhh, w1m, b1v,
      WHH_HI, WHH_LO, WIH_HI, WIH_LO, WPR_HI, WPR_LO, BSUM, B1C);
  embed_kernel<<<1536, 320, 0, stream>>>(widx, pidx, wemb, temb,
      XA_HI, XA_LO, XB_HI, XB_LO);

  for (int layer = 0; layer < 4; ++layer) {
    const unsigned short* xin_hi = (layer & 1) ? XB_HI : XA_HI;
    const unsigned short* xin_lo = (layer & 1) ? XB_LO : XA_LO;
    unsigned short* xo_hi = (layer & 1) ? XA_HI : XB_HI;
    unsigned short* xo_lo = (layer & 1) ? XA_LO : XB_LO;
    const float* bsl = BSUM + layer * 2 * 640;
    if (layer == 0) {
      pregemm_kernel<5><<<dim3(96, 2), 512, 0, stream>>>(
          xin_hi, xin_lo, WIH_HI, WIH_LO, bsl, PRE);
    } else {
      size_t wo = 204800ull + (size_t)(layer - 1) * 409600ull;
      pregemm_kernel<10><<<dim3(96, 2), 512, 0, stream>>>(
          xin_hi, xin_lo, WIH_HI + wo, WIH_LO + wo, bsl, PRE);
    }
    scan_kernel<<<2, 256, 0, stream>>>(PRE, WHH_HI, WHH_LO, xo_hi, xo_lo, layer);
  }
  // layer-3 output sits in XA; poly -> XB; proj -> AD; combine -> out
  poly_kernel<<<1920, 256, 0, stream>>>(XA_HI, XA_LO, XB_HI, XB_LO, w1, w2, w3, w4);
  proj_kernel<<<96, 512, 0, stream>>>(XB_HI, XB_LO, WPR_HI, WPR_LO, B1C, AD);
  combine_kernel<<<192, 768, 0, stream>>>(AD, w2m, b2v, out);
}

// Round 4
// 1120.109 us; speedup vs baseline: 2.7208x; 2.7208x over previous
//
#include <hip/hip_runtime.h>

// ---------------- types / helpers ----------------
typedef __attribute__((ext_vector_type(8))) _Float16 half8;
typedef __attribute__((ext_vector_type(4))) _Float16 half4;
typedef __attribute__((ext_vector_type(4))) float float4v;

__device__ __forceinline__ float4v mfma16h(half8 a, half8 b, float4v c) {
  return __builtin_amdgcn_mfma_f32_16x16x32_f16(a, b, c, 0, 0, 0);
}

__device__ __forceinline__ half8 cat44h(half4 a, half4 b) {
  half8 r;
  r[0]=a[0]; r[1]=a[1]; r[2]=a[2]; r[3]=a[3];
  r[4]=b[0]; r[5]=b[1]; r[6]=b[2]; r[7]=b[3];
  return r;
}

__device__ __forceinline__ void split_f16(float x, _Float16& hi, _Float16& lo) {
  hi = (_Float16)x;                 // RNE
  lo = (_Float16)(x - (float)hi);
}

#define KLOG2E 1.442695041f
__device__ __forceinline__ float fast_sig(float x) {
  float z = __builtin_amdgcn_exp2f(-KLOG2E * x);
  return __builtin_amdgcn_rcpf(1.f + z);
}
__device__ __forceinline__ float fast_tanh(float x) {
  float z = __builtin_amdgcn_exp2f(2.f * KLOG2E * x);
  return 1.f - 2.f * __builtin_amdgcn_rcpf(1.f + z);
}

// sizes
// B=16 L=96 H=150 4H=600(pad 640) EMB=150(pad 160) 2H=300(pad 320)
// rows indexed row = t*16 + b
// fragment slot formula (same for A and B operands; permutation cancels):
//   k(lane,e) = 32*kc + 16*(e>>2) + 4*(lane>>4) + (e&3)

// ---------------- prep: fp16 weight fragments (single precision weights) ----------
__global__ void prep_kernel(
    const float* __restrict__ Wih0,   // [2][600][150]
    const float* __restrict__ WihR,   // [3][2][600][300]
    const float* __restrict__ Whh,    // [4][2][600][150]
    const float* __restrict__ bih,    // [4][2][600]
    const float* __restrict__ bhh,    // [4][2][600]
    const float* __restrict__ w1m,    // [100][600]
    const float* __restrict__ b1v,    // [100]
    _Float16* __restrict__ whh_f,
    _Float16* __restrict__ wih_f,
    _Float16* __restrict__ wpr_f,
    float* __restrict__ bsum, float* __restrict__ b1cat)
{
  const int N_whh  = 8 * 40 * 5 * 512;   // 819200
  const int N_wih0 = 2 * 40 * 5 * 512;   // 204800
  const int N_wihr = 6 * 40 * 10 * 512;  // 1228800
  const int N_wpr  = 16 * 10 * 512;      // 81920
  const int N_bs   = 8 * 640;            // 5120
  const int total  = N_whh + N_wih0 + N_wihr + N_wpr + N_bs + 256;
  for (int i = blockIdx.x * blockDim.x + threadIdx.x; i < total;
       i += gridDim.x * blockDim.x) {
    int idx = i;
    if (idx < N_whh) {
      int e = idx & 7, lane = (idx >> 3) & 63, r = idx >> 9;
      int kc = r % 5; r /= 5; int nt = r % 40; int ld = r / 40;
      int g = 16 * nt + (lane & 15);
      int j = 32 * kc + 16 * (e >> 2) + 4 * (lane >> 4) + (e & 3);
      float v = (g < 600 && j < 150) ? Whh[((size_t)ld * 600 + g) * 150 + j] : 0.f;
      whh_f[idx] = (_Float16)v;
      continue;
    }
    idx -= N_whh;
    if (idx < N_wih0) {
      int e = idx & 7, lane = (idx >> 3) & 63, r = idx >> 9;
      int kc = r % 5; r /= 5; int nt = r % 40; int dir = r / 40;
      int g = 16 * nt + (lane & 15);
      int j = 32 * kc + 16 * (e >> 2) + 4 * (lane >> 4) + (e & 3);
      float v = (g < 600 && j < 150) ? Wih0[((size_t)dir * 600 + g) * 150 + j] : 0.f;
      wih_f[idx] = (_Float16)v;
      continue;
    }
    idx -= N_wih0;
    if (idx < N_wihr) {
      int e = idx & 7, lane = (idx >> 3) & 63, r = idx >> 9;
      int kc = r % 10; r /= 10; int nt = r % 40; int ld = r / 40;
      int g = 16 * nt + (lane & 15);
      int j = 32 * kc + 16 * (e >> 2) + 4 * (lane >> 4) + (e & 3);
      float v = (g < 600 && j < 300) ? WihR[((size_t)ld * 600 + g) * 300 + j] : 0.f;
      wih_f[N_wih0 + idx] = (_Float16)v;
      continue;
    }
    idx -= N_wihr;
    if (idx < N_wpr) {
      int e = idx & 7, lane = (idx >> 3) & 63, r = idx >> 9;
      int kc = r % 10; int nt = r / 10;
      int ko = 16 * nt + (lane & 15);
      int j = 32 * kc + 16 * (e >> 2) + 4 * (lane >> 4) + (e & 3);
      float v = 0.f;
      if (j < 300) {
        if (ko < 100) v = w1m[(size_t)ko * 600 + j];
        else if (ko < 200) v = w1m[(size_t)(ko - 100) * 600 + 300 + j];
      }
      wpr_f[idx] = (_Float16)v;
      continue;
    }
    idx -= N_wpr;
    if (idx < N_bs) {
      int ld = idx / 640, g = idx - 640 * ld;
      bsum[idx] = (g < 600) ? bih[ld * 600 + g] + bhh[ld * 600 + g] : 0.f;
      continue;
    }
    idx -= N_bs;
    b1cat[idx] = (idx < 100) ? b1v[idx] : ((idx < 200) ? b1v[idx - 100] : 0.f);
  }
}

// ---------------- embedding gather -> fp16 hi/lo ----------------
__global__ void embed_kernel(const int* __restrict__ widx, const int* __restrict__ pidx,
    const float* __restrict__ wemb, const float* __restrict__ temb,
    _Float16* __restrict__ xa_h, _Float16* __restrict__ xa_l,
    _Float16* __restrict__ xb_h, _Float16* __restrict__ xb_l)
{
  int row = blockIdx.x;       // t*16 + b
  int j = threadIdx.x;        // 0..319
  int b = row & 15, t = row >> 4;
  float v = 0.f;
  if (j < 100) v = wemb[(size_t)widx[b * 96 + t] * 100 + j];
  else if (j < 150) v = temb[(size_t)pidx[b * 96 + t] * 50 + (j - 100)];
  _Float16 h, l; split_f16(v, h, l);
  size_t o = (size_t)row * 320 + j;
  xa_h[o] = h; xa_l[o] = l;
  if (j >= 300) { xb_h[o] = (_Float16)0.f; xb_l[o] = (_Float16)0.f; }
}

// ---------------- pre-GEMM: pre[d][t][b][g] = x @ Wih^T + b_ih + b_hh ----------------
template <int KC>
__global__ __launch_bounds__(512) void pregemm_kernel(
    const _Float16* __restrict__ x_h, const _Float16* __restrict__ x_l,
    const _Float16* __restrict__ wih_f,
    const float* __restrict__ bsum_l,
    float* __restrict__ pre)            // [2][96][16][640]
{
  const int t = blockIdx.x, dir = blockIdx.y;
  const int tid = threadIdx.x, wv = tid >> 6, lane = tid & 63;
  const int lrow = lane & 15, lgrp = lane >> 4;
  const _Float16* wf = wih_f + (size_t)dir * 40 * KC * 512;
  float4v acc[5];
#pragma unroll
  for (int tt = 0; tt < 5; ++tt) acc[tt] = (float4v){0.f, 0.f, 0.f, 0.f};
  const size_t arow = ((size_t)t * 16 + lrow) * 320;
#pragma unroll
  for (int kc = 0; kc < KC; ++kc) {
    int co = 32 * kc + 4 * lgrp;
    half8 ah = cat44h(*(const half4*)(x_h + arow + co),
                      *(const half4*)(x_h + arow + co + 16));
    half8 al = cat44h(*(const half4*)(x_l + arow + co),
                      *(const half4*)(x_l + arow + co + 16));
#pragma unroll
    for (int tt = 0; tt < 5; ++tt) {
      int nt = 5 * wv + tt;
      const size_t wo = ((size_t)(nt * KC + kc) * 64 + lane) * 8;
      half8 bw = *(const half8*)(wf + wo);
      acc[tt] = mfma16h(ah, bw, acc[tt]);
      acc[tt] = mfma16h(al, bw, acc[tt]);
    }
  }
  float* po = pre + ((size_t)dir * 96 + t) * 16 * 640;
  const float* bs = bsum_l + dir * 640;
#pragma unroll
  for (int tt = 0; tt < 5; ++tt) {
    int g = 16 * (5 * wv + tt) + lrow;
    float bv = bs[g];
#pragma unroll
    for (int jj = 0; jj < 4; ++jj)
      po[(size_t)(4 * lgrp + jj) * 640 + g] = acc[tt][jj] + bv;
  }
}

// ---------------- sequential LSTM scan, one 8-wave block per direction ----------------
// fp16 single weights: 25 half8 = 100 VGPR resident/wave; total demand ~175 < 256.
__global__ __launch_bounds__(512, 2) void scan_kernel(
    const float* __restrict__ pre,                 // [2][96][16][640]
    const _Float16* __restrict__ whh_f,
    _Float16* __restrict__ xo_h, _Float16* __restrict__ xo_l, // [1536][320]
    int layer)
{
  const int dir = blockIdx.x;
  const int tid = threadIdx.x, wv = tid >> 6, lane = tid & 63;
  const int lrow = lane & 15, lgrp = lane >> 4;

  // h in MFMA A-fragment order: pos = b*168 + kc*32 + q*8 + e   (q = lane>>4)
  __shared__ __align__(16) _Float16 h_h[16 * 168];
  __shared__ __align__(16) _Float16 h_l[16 * 168];
  __shared__ float gA[16 * 644];

  for (int i = tid; i < 16 * 168; i += 512) { h_h[i] = (_Float16)0.f; h_l[i] = (_Float16)0.f; }

  // Whh fragments resident: 5 N-tiles x 5 kc per wave
  const _Float16* b_base = whh_f + (size_t)(layer * 2 + dir) * 40 * 5 * 512;
  half8 Bw[5][5];
#pragma unroll
  for (int tt = 0; tt < 5; ++tt)
#pragma unroll
    for (int kc = 0; kc < 5; ++kc) {
      size_t o = ((size_t)((5 * wv + tt) * 5 + kc) * 64 + lane) * 8;
      Bw[tt][kc] = *(const half8*)(b_base + o);
    }

  float cst[5];
#pragma unroll
  for (int ii = 0; ii < 5; ++ii) cst[ii] = 0.f;

  const float* preD = pre + (size_t)dir * 96 * 16 * 640;
  __syncthreads();

#pragma unroll 1
  for (int step = 0; step < 96; ++step) {
    const int t = dir ? (95 - step) : step;
    const float* pt = preD + (size_t)t * 16 * 640;

    // acc initialized from PRE (C-input carries x@Wih + biases)
    float4v acc[5];
#pragma unroll
    for (int tt = 0; tt < 5; ++tt) {
      int g = 16 * (5 * wv + tt) + lrow;
#pragma unroll
      for (int jj = 0; jj < 4; ++jj)
        acc[tt][jj] = pt[(size_t)(4 * lgrp + jj) * 640 + g];
    }

#pragma unroll
    for (int kc = 0; kc < 5; ++kc) {
      const int ao = lrow * 168 + kc * 32 + lgrp * 8;
      half8 ah = *(const half8*)(h_h + ao);
      half8 al = *(const half8*)(h_l + ao);
#pragma unroll
      for (int tt = 0; tt < 5; ++tt) {
        acc[tt] = mfma16h(ah, Bw[tt][kc], acc[tt]);
        acc[tt] = mfma16h(al, Bw[tt][kc], acc[tt]);
      }
    }

    // raw pre-activations to LDS (nonlinearity in state phase)
#pragma unroll
    for (int tt = 0; tt < 5; ++tt) {
      int g = 16 * (5 * wv + tt) + lrow;
#pragma unroll
      for (int jj = 0; jj < 4; ++jj)
        gA[(4 * lgrp + jj) * 644 + g] = acc[tt][jj];
    }
    __syncthreads();

    // state update: thread owns fixed (b,j) cells, c kept in registers
#pragma unroll
    for (int ii = 0; ii < 5; ++ii) {
      int e = tid + 512 * ii;
      if (e < 2400) {
        int b = e / 150;
        int j = e - 150 * b;
        const float* gb = gA + b * 644 + j;
        float i_ = fast_sig(gb[0]);
        float f_ = fast_sig(gb[150]);
        float g_ = fast_tanh(gb[300]);
        float o_ = fast_sig(gb[450]);
        float c = f_ * cst[ii] + i_ * g_;
        cst[ii] = c;
        float h = o_ * fast_tanh(c);
        _Float16 hh, hl; split_f16(h, hh, hl);
        int kc = j >> 5, w = j & 31;
        int off = b * 168 + kc * 32 + ((w >> 2) & 3) * 8 + (w >> 4) * 4 + (w & 3);
        h_h[off] = hh; h_l[off] = hl;
        size_t gout = ((size_t)t * 16 + b) * 320 + dir * 150 + j;
        xo_h[gout] = hh; xo_l[gout] = hl;
      }
    }
    __syncthreads();
  }
}

// ---------------- elementwise degree-4 polynomial ----------------
__global__ void poly_kernel(const _Float16* __restrict__ xi_h,
    const _Float16* __restrict__ xi_l,
    _Float16* __restrict__ xo_h, _Float16* __restrict__ xo_l,
    const float* __restrict__ w1, const float* __restrict__ w2,
    const float* __restrict__ w3, const float* __restrict__ w4)
{
  int i = blockIdx.x * 256 + threadIdx.x;
  if (i >= 1536 * 320) return;
  float x = (float)xi_h[i] + (float)xi_l[i];
  float p = x * (w1[0] + x * (w2[0] + x * (w3[0] + x * w4[0])));
  _Float16 h, l; split_f16(p, h, l);
  xo_h[i] = h; xo_l[i] = l;
}

// ---------------- projection: AD[row][0:100]=A+b1, [100:200]=D ----------------
__global__ __launch_bounds__(512) void proj_kernel(
    const _Float16* __restrict__ p_h, const _Float16* __restrict__ p_l,
    const _Float16* __restrict__ wpr_f,
    const float* __restrict__ b1cat,
    float* __restrict__ AD)   // [1536][256]
{
  const int t = blockIdx.x;
  const int tid = threadIdx.x, wv = tid >> 6, lane = tid & 63;
  const int lrow = lane & 15, lgrp = lane >> 4;
  float4v acc[2] = {{0.f, 0.f, 0.f, 0.f}, {0.f, 0.f, 0.f, 0.f}};
  const size_t arow = ((size_t)t * 16 + lrow) * 320;
#pragma unroll
  for (int kc = 0; kc < 10; ++kc) {
    int co = 32 * kc + 4 * lgrp;
    half8 ah = cat44h(*(const half4*)(p_h + arow + co),
                      *(const half4*)(p_h + arow + co + 16));
    half8 al = cat44h(*(const half4*)(p_l + arow + co),
                      *(const half4*)(p_l + arow + co + 16));
#pragma unroll
    for (int tt = 0; tt < 2; ++tt) {
      int nt = 2 * wv + tt;
      size_t wo = ((size_t)(nt * 10 + kc) * 64 + lane) * 8;
      half8 bw = *(const half8*)(wpr_f + wo);
      acc[tt] = mfma16h(ah, bw, acc[tt]);
      acc[tt] = mfma16h(al, bw, acc[tt]);
    }
  }
#pragma unroll
  for (int tt = 0; tt < 2; ++tt) {
    int ko = 16 * (2 * wv + tt) + lrow;
    float bv = b1cat[ko];
#pragma unroll
    for (int jj = 0; jj < 4; ++jj)
      AD[((size_t)t * 16 + 4 * lgrp + jj) * 256 + ko] = acc[tt][jj] + bv;
  }
}

// ---------------- combine: out[lh][b][ld] = b2 + sum_k w2[k]*tanh(A+D) ----------------
__global__ __launch_bounds__(768) void combine_kernel(
    const float* __restrict__ AD, const float* __restrict__ w2v,
    const float* __restrict__ b2v, float* __restrict__ out)
{
  const int bb = blockIdx.x & 15, lt = blockIdx.x >> 4;
  const int tid = threadIdx.x;
  __shared__ float Dl[100 * 97];  // [k][ld], stride 97
  __shared__ float Al[100 * 9];   // [k][lh], stride 9
  __shared__ float w2s[100];
  for (int i = tid; i < 96 * 32; i += 768) {
    int ld = i >> 5, f4 = i & 31;
    if (f4 < 25) {
      float4v v = *(const float4v*)(AD + ((size_t)ld * 16 + bb) * 256 + 100 + 4 * f4);
      int k0 = 4 * f4;
      Dl[(k0 + 0) * 97 + ld] = v[0];
      Dl[(k0 + 1) * 97 + ld] = v[1];
      Dl[(k0 + 2) * 97 + ld] = v[2];
      Dl[(k0 + 3) * 97 + ld] = v[3];
    }
  }
  for (int i = tid; i < 8 * 32; i += 768) {
    int lh = i >> 5, f4 = i & 31;
    if (f4 < 25) {
      int lseq = lt * 8 + lh;
      float4v v = *(const float4v*)(AD + ((size_t)lseq * 16 + bb) * 256 + 4 * f4);
      int k0 = 4 * f4;
      Al[(k0 + 0) * 9 + lh] = v[0];
      Al[(k0 + 1) * 9 + lh] = v[1];
      Al[(k0 + 2) * 9 + lh] = v[2];
      Al[(k0 + 3) * 9 + lh] = v[3];
    }
  }
  if (tid < 100) w2s[tid] = w2v[tid];
  __syncthreads();
  int lh = tid / 96, ld = tid - 96 * lh;
  float s = 0.f;
#pragma unroll 4
  for (int k = 0; k < 100; ++k) {
    float x = Al[k * 9 + lh] + Dl[k * 97 + ld];
    s += w2s[k] * fast_tanh(x);
  }
  out[((size_t)(lt * 8 + lh) * 16 + bb) * 96 + ld] = s + b2v[0];
}

// ---------------- host ----------------
extern "C" void kernel_launch(void* const* d_in, const int* in_sizes, int n_in,
                              void* d_out, int out_size, void* d_ws, size_t ws_size,
                              hipStream_t stream)
{
  const int*   widx = (const int*)d_in[0];
  const int*   pidx = (const int*)d_in[1];
  const float* wemb = (const float*)d_in[3];
  const float* temb = (const float*)d_in[4];
  const float* Wih0 = (const float*)d_in[5];
  const float* WihR = (const float*)d_in[6];
  const float* Whh  = (const float*)d_in[7];
  const float* bih  = (const float*)d_in[8];
  const float* bhh  = (const float*)d_in[9];
  const float* w1   = (const float*)d_in[10];
  const float* w2   = (const float*)d_in[11];
  const float* w3   = (const float*)d_in[12];
  const float* w4   = (const float*)d_in[13];
  const float* w1m  = (const float*)d_in[14];
  const float* b1v  = (const float*)d_in[15];
  const float* w2m  = (const float*)d_in[16];
  const float* b2v  = (const float*)d_in[17];
  float* out = (float*)d_out;

  char* ws = (char*)d_ws;
  size_t off = 0;
  auto alloc = [&](size_t bytes) -> char* {
    char* p = ws + off;
    off = (off + bytes + 255) & ~(size_t)255;
    return p;
  };
  _Float16* WHH_F = (_Float16*)alloc(819200ull * 2);
  _Float16* WIH_F = (_Float16*)alloc(1433600ull * 2);
  _Float16* WPR_F = (_Float16*)alloc(81920ull * 2);
  float* BSUM = (float*)alloc(5120ull * 4);
  float* B1C  = (float*)alloc(256ull * 4);
  _Float16* XA_H = (_Float16*)alloc(491520ull * 2);
  _Float16* XA_L = (_Float16*)alloc(491520ull * 2);
  _Float16* XB_H = (_Float16*)alloc(491520ull * 2);
  _Float16* XB_L = (_Float16*)alloc(491520ull * 2);
  float* PRE = (float*)alloc(1966080ull * 4);
  float* AD  = (float*)alloc(1536ull * 256 * 4);

  prep_kernel<<<512, 256, 0, stream>>>(Wih0, WihR, Whh, bih, bhh, w1m, b1v,
      WHH_F, WIH_F, WPR_F, BSUM, B1C);
  embed_kernel<<<1536, 320, 0, stream>>>(widx, pidx, wemb, temb,
      XA_H, XA_L, XB_H, XB_L);

  for (int layer = 0; layer < 4; ++layer) {
    const _Float16* xin_h = (layer & 1) ? XB_H : XA_H;
    const _Float16* xin_l = (layer & 1) ? XB_L : XA_L;
    _Float16* xo_h = (layer & 1) ? XA_H : XB_H;
    _Float16* xo_l = (layer & 1) ? XA_L : XB_L;
    const float* bsl = BSUM + layer * 2 * 640;
    if (layer == 0) {
      pregemm_kernel<5><<<dim3(96, 2), 512, 0, stream>>>(
          xin_h, xin_l, WIH_F, bsl, PRE);
    } else {
      size_t wo = 204800ull + (size_t)(layer - 1) * 409600ull;
      pregemm_kernel<10><<<dim3(96, 2), 512, 0, stream>>>(
          xin_h, xin_l, WIH_F + wo, bsl, PRE);
    }
    scan_kernel<<<2, 512, 0, stream>>>(PRE, WHH_F, xo_h, xo_l, layer);
  }
  // layer-3 output sits in XA; poly -> XB; proj -> AD; combine -> out
  poly_kernel<<<1920, 256, 0, stream>>>(XA_H, XA_L, XB_H, XB_L, w1, w2, w3, w4);
  proj_kernel<<<96, 512, 0, stream>>>(XB_H, XB_L, WPR_F, B1C, AD);
  combine_kernel<<<192, 768, 0, stream>>>(AD, w2m, b2v, out);
}

// Round 5
// 825.002 us; speedup vs baseline: 3.6940x; 1.3577x over previous
//
#include <hip/hip_runtime.h>

// ---------------- types / helpers ----------------
typedef __attribute__((ext_vector_type(8))) _Float16 half8;
typedef __attribute__((ext_vector_type(4))) _Float16 half4;
typedef __attribute__((ext_vector_type(4))) float float4v;

__device__ __forceinline__ float4v mfma16h(half8 a, half8 b, float4v c) {
  return __builtin_amdgcn_mfma_f32_16x16x32_f16(a, b, c, 0, 0, 0);
}

__device__ __forceinline__ half8 cat44h(half4 a, half4 b) {
  half8 r;
  r[0]=a[0]; r[1]=a[1]; r[2]=a[2]; r[3]=a[3];
  r[4]=b[0]; r[5]=b[1]; r[6]=b[2]; r[7]=b[3];
  return r;
}

__device__ __forceinline__ void split_f16(float x, _Float16& hi, _Float16& lo) {
  hi = (_Float16)x;                 // RNE
  lo = (_Float16)(x - (float)hi);
}

#define KLOG2E 1.442695041f
__device__ __forceinline__ float fast_sig(float x) {
  float z = __builtin_amdgcn_exp2f(-KLOG2E * x);
  return __builtin_amdgcn_rcpf(1.f + z);
}
__device__ __forceinline__ float fast_tanh(float x) {
  float z = __builtin_amdgcn_exp2f(2.f * KLOG2E * x);
  return 1.f - 2.f * __builtin_amdgcn_rcpf(1.f + z);
}

// sizes: B=16 L=96 H=150 4H=600(pad 640) EMB=150(pad 160) 2H=300(pad 320)
// rows indexed row = t*16 + b
// fragment slot formula (same for A and B operands; permutation cancels):
//   k(lane,e) = 32*kc + 16*(e>>2) + 4*(lane>>4) + (e&3)
// GATE-QUAD permutation (Wih/Whh/bsum only): output tile nt = jg*4 + gate,
//   source row g_src = gate*150 + jg*16 + lrow  (jg = j/16). One wave owns
//   tiles 4w..4w+3 -> all four gates of cell (b, j=16w+lrow) land in one
//   thread's C-fragments. xo / proj layouts unchanged.

// ---------------- prep: fp16 weight fragments, gate-quad permuted ----------
__global__ void prep_kernel(
    const float* __restrict__ Wih0,   // [2][600][150]
    const float* __restrict__ WihR,   // [3][2][600][300]
    const float* __restrict__ Whh,    // [4][2][600][150]
    const float* __restrict__ bih,    // [4][2][600]
    const float* __restrict__ bhh,    // [4][2][600]
    const float* __restrict__ w1m,    // [100][600]
    const float* __restrict__ b1v,    // [100]
    _Float16* __restrict__ whh_f,
    _Float16* __restrict__ wih_f,
    _Float16* __restrict__ wpr_f,
    float* __restrict__ bsum, float* __restrict__ b1cat)
{
  const int N_whh  = 8 * 40 * 5 * 512;   // 819200
  const int N_wih0 = 2 * 40 * 5 * 512;   // 204800
  const int N_wihr = 6 * 40 * 10 * 512;  // 1228800
  const int N_wpr  = 16 * 10 * 512;      // 81920
  const int N_bs   = 8 * 640;            // 5120
  const int total  = N_whh + N_wih0 + N_wihr + N_wpr + N_bs + 256;
  for (int i = blockIdx.x * blockDim.x + threadIdx.x; i < total;
       i += gridDim.x * blockDim.x) {
    int idx = i;
    if (idx < N_whh) {
      int e = idx & 7, lane = (idx >> 3) & 63, r = idx >> 9;
      int kc = r % 5; r /= 5; int nt = r % 40; int ld = r / 40;
      int jrow = (nt >> 2) * 16 + (lane & 15);
      int g = (nt & 3) * 150 + jrow;
      int k = 32 * kc + 16 * (e >> 2) + 4 * (lane >> 4) + (e & 3);
      float v = (jrow < 150 && k < 150) ? Whh[((size_t)ld * 600 + g) * 150 + k] : 0.f;
      whh_f[idx] = (_Float16)v;
      continue;
    }
    idx -= N_whh;
    if (idx < N_wih0) {
      int e = idx & 7, lane = (idx >> 3) & 63, r = idx >> 9;
      int kc = r % 5; r /= 5; int nt = r % 40; int dir = r / 40;
      int jrow = (nt >> 2) * 16 + (lane & 15);
      int g = (nt & 3) * 150 + jrow;
      int k = 32 * kc + 16 * (e >> 2) + 4 * (lane >> 4) + (e & 3);
      float v = (jrow < 150 && k < 150) ? Wih0[((size_t)dir * 600 + g) * 150 + k] : 0.f;
      wih_f[idx] = (_Float16)v;
      continue;
    }
    idx -= N_wih0;
    if (idx < N_wihr) {
      int e = idx & 7, lane = (idx >> 3) & 63, r = idx >> 9;
      int kc = r % 10; r /= 10; int nt = r % 40; int ld = r / 40;
      int jrow = (nt >> 2) * 16 + (lane & 15);
      int g = (nt & 3) * 150 + jrow;
      int k = 32 * kc + 16 * (e >> 2) + 4 * (lane >> 4) + (e & 3);
      float v = (jrow < 150 && k < 300) ? WihR[((size_t)ld * 600 + g) * 300 + k] : 0.f;
      wih_f[N_wih0 + idx] = (_Float16)v;
      continue;
    }
    idx -= N_wihr;
    if (idx < N_wpr) {
      int e = idx & 7, lane = (idx >> 3) & 63, r = idx >> 9;
      int kc = r % 10; int nt = r / 10;
      int ko = 16 * nt + (lane & 15);
      int k = 32 * kc + 16 * (e >> 2) + 4 * (lane >> 4) + (e & 3);
      float v = 0.f;
      if (k < 300) {
        if (ko < 100) v = w1m[(size_t)ko * 600 + k];
        else if (ko < 200) v = w1m[(size_t)(ko - 100) * 600 + 300 + k];
      }
      wpr_f[idx] = (_Float16)v;
      continue;
    }
    idx -= N_wpr;
    if (idx < N_bs) {
      int ld = idx / 640, gp = idx - 640 * ld;
      int nt = gp >> 4, lrow = gp & 15;
      int jrow = (nt >> 2) * 16 + lrow;
      int g = (nt & 3) * 150 + jrow;
      bsum[idx] = (jrow < 150) ? bih[ld * 600 + g] + bhh[ld * 600 + g] : 0.f;
      continue;
    }
    idx -= N_bs;
    b1cat[idx] = (idx < 100) ? b1v[idx] : ((idx < 200) ? b1v[idx - 100] : 0.f);
  }
}

// ---------------- embedding gather -> fp16 hi/lo ----------------
__global__ void embed_kernel(const int* __restrict__ widx, const int* __restrict__ pidx,
    const float* __restrict__ wemb, const float* __restrict__ temb,
    _Float16* __restrict__ xa_h, _Float16* __restrict__ xa_l,
    _Float16* __restrict__ xb_h, _Float16* __restrict__ xb_l)
{
  int row = blockIdx.x;       // t*16 + b
  int j = threadIdx.x;        // 0..319
  int b = row & 15, t = row >> 4;
  float v = 0.f;
  if (j < 100) v = wemb[(size_t)widx[b * 96 + t] * 100 + j];
  else if (j < 150) v = temb[(size_t)pidx[b * 96 + t] * 50 + (j - 100)];
  _Float16 h, l; split_f16(v, h, l);
  size_t o = (size_t)row * 320 + j;
  xa_h[o] = h; xa_l[o] = l;
  if (j >= 300) { xb_h[o] = (_Float16)0.f; xb_l[o] = (_Float16)0.f; }
}

// ---------------- pre-GEMM: pre[d][t][b][g'] = x @ Wih^T + b (permuted g') ----------
template <int KC>
__global__ __launch_bounds__(512) void pregemm_kernel(
    const _Float16* __restrict__ x_h, const _Float16* __restrict__ x_l,
    const _Float16* __restrict__ wih_f,
    const float* __restrict__ bsum_l,
    float* __restrict__ pre)            // [2][96][16][640]
{
  const int t = blockIdx.x, dir = blockIdx.y;
  const int tid = threadIdx.x, wv = tid >> 6, lane = tid & 63;
  const int lrow = lane & 15, lgrp = lane >> 4;
  const _Float16* wf = wih_f + (size_t)dir * 40 * KC * 512;
  float4v acc[5];
#pragma unroll
  for (int tt = 0; tt < 5; ++tt) acc[tt] = (float4v){0.f, 0.f, 0.f, 0.f};
  const size_t arow = ((size_t)t * 16 + lrow) * 320;
#pragma unroll
  for (int kc = 0; kc < KC; ++kc) {
    int co = 32 * kc + 4 * lgrp;
    half8 ah = cat44h(*(const half4*)(x_h + arow + co),
                      *(const half4*)(x_h + arow + co + 16));
    half8 al = cat44h(*(const half4*)(x_l + arow + co),
                      *(const half4*)(x_l + arow + co + 16));
#pragma unroll
    for (int tt = 0; tt < 5; ++tt) {
      int nt = 5 * wv + tt;
      const size_t wo = ((size_t)(nt * KC + kc) * 64 + lane) * 8;
      half8 bw = *(const half8*)(wf + wo);
      acc[tt] = mfma16h(ah, bw, acc[tt]);
      acc[tt] = mfma16h(al, bw, acc[tt]);
    }
  }
  float* po = pre + ((size_t)dir * 96 + t) * 16 * 640;
  const float* bs = bsum_l + dir * 640;
#pragma unroll
  for (int tt = 0; tt < 5; ++tt) {
    int g = 16 * (5 * wv + tt) + lrow;
    float bv = bs[g];
#pragma unroll
    for (int jj = 0; jj < 4; ++jj)
      po[(size_t)(4 * lgrp + jj) * 640 + g] = acc[tt][jj] + bv;
  }
}

// ---------------- sequential LSTM scan: 10 waves, gates thread-local ----------------
// wave w owns gate-quad tiles 4w..4w+3 -> acc[0..3][jj] = i,f,g,o of (b,j=16w+lrow).
// No gA buffer, ONE barrier/step, double-buffered h in LDS, PRE prefetched.
__global__ __launch_bounds__(640, 1) void scan_kernel(
    const float* __restrict__ pre,                 // [2][96][16][640] (g' permuted)
    const _Float16* __restrict__ whh_f,
    _Float16* __restrict__ xo_h, _Float16* __restrict__ xo_l, // [1536][320]
    int layer)
{
  const int dir = blockIdx.x;
  const int tid = threadIdx.x, wv = tid >> 6, lane = tid & 63;
  const int lrow = lane & 15, lgrp = lane >> 4;

  // h in MFMA A-fragment order: pos = b*168 + kc*32 + q*8 + e   (q = lane>>4)
  __shared__ __align__(16) _Float16 hb[2][2][16 * 168];  // [buf][hi/lo][...]

  for (int i = tid; i < 2 * 2 * 16 * 168; i += 640)
    (&hb[0][0][0])[i] = (_Float16)0.f;

  // Whh fragments resident: 4 gate-quad tiles x 5 kc per wave (80 VGPR)
  const _Float16* b_base = whh_f + (size_t)(layer * 2 + dir) * 40 * 5 * 512;
  half8 Bw[4][5];
#pragma unroll
  for (int tt = 0; tt < 4; ++tt)
#pragma unroll
    for (int kc = 0; kc < 5; ++kc) {
      size_t o = ((size_t)((4 * wv + tt) * 5 + kc) * 64 + lane) * 8;
      Bw[tt][kc] = *(const half8*)(b_base + o);
    }

  float cst[4] = {0.f, 0.f, 0.f, 0.f};
  const int j = 16 * wv + lrow;          // this thread's cell column
  const int kcj = j >> 5, wj = j & 31;   // h-fragment slot for (b, j)
  const int hoff = kcj * 32 + ((wj >> 2) & 3) * 8 + (wj >> 4) * 4 + (wj & 3);

  const float* preD = pre + (size_t)dir * 96 * 16 * 640;

  // prefetch PRE for step 0
  float4v pf[4];
  {
    const float* pt = preD + (size_t)(dir ? 95 : 0) * 16 * 640;
#pragma unroll
    for (int tt = 0; tt < 4; ++tt) {
      int gp = 16 * (4 * wv + tt) + lrow;
#pragma unroll
      for (int jj = 0; jj < 4; ++jj)
        pf[tt][jj] = pt[(size_t)(4 * lgrp + jj) * 640 + gp];
    }
  }
  __syncthreads();

#pragma unroll 1
  for (int step = 0; step < 96; ++step) {
    const int t = dir ? (95 - step) : step;

    float4v acc[4];
#pragma unroll
    for (int tt = 0; tt < 4; ++tt) acc[tt] = pf[tt];

    const _Float16* hh = hb[step & 1][0];
    const _Float16* hl = hb[step & 1][1];
#pragma unroll
    for (int kc = 0; kc < 5; ++kc) {
      const int ao = lrow * 168 + kc * 32 + lgrp * 8;
      half8 ah = *(const half8*)(hh + ao);
      half8 al = *(const half8*)(hl + ao);
#pragma unroll
      for (int tt = 0; tt < 4; ++tt) {
        acc[tt] = mfma16h(ah, Bw[tt][kc], acc[tt]);
        acc[tt] = mfma16h(al, Bw[tt][kc], acc[tt]);
      }
    }

    // prefetch next step's PRE (hidden under state phase)
    if (step < 95) {
      const float* pt = preD + (size_t)(dir ? (94 - step) : (step + 1)) * 16 * 640;
#pragma unroll
      for (int tt = 0; tt < 4; ++tt) {
        int gp = 16 * (4 * wv + tt) + lrow;
#pragma unroll
        for (int jj = 0; jj < 4; ++jj)
          pf[tt][jj] = pt[(size_t)(4 * lgrp + jj) * 640 + gp];
      }
    }

    // state phase: gates already thread-local (tt = gate: i,f,g,o)
    _Float16* nhh = hb[(step + 1) & 1][0];
    _Float16* nhl = hb[(step + 1) & 1][1];
#pragma unroll
    for (int jj = 0; jj < 4; ++jj) {
      int b = 4 * lgrp + jj;
      float i_ = fast_sig(acc[0][jj]);
      float f_ = fast_sig(acc[1][jj]);
      float g_ = fast_tanh(acc[2][jj]);
      float o_ = fast_sig(acc[3][jj]);
      float c = f_ * cst[jj] + i_ * g_;
      cst[jj] = c;
      float h = o_ * fast_tanh(c);
      _Float16 hhv, hlv; split_f16(h, hhv, hlv);
      nhh[b * 168 + hoff] = hhv;
      nhl[b * 168 + hoff] = hlv;
      if (j < 150) {
        size_t gout = ((size_t)t * 16 + b) * 320 + dir * 150 + j;
        xo_h[gout] = hhv;
        xo_l[gout] = hlv;
      }
    }
    __syncthreads();
  }
}

// ---------------- elementwise degree-4 polynomial ----------------
__global__ void poly_kernel(const _Float16* __restrict__ xi_h,
    const _Float16* __restrict__ xi_l,
    _Float16* __restrict__ xo_h, _Float16* __restrict__ xo_l,
    const float* __restrict__ w1, const float* __restrict__ w2,
    const float* __restrict__ w3, const float* __restrict__ w4)
{
  int i = blockIdx.x * 256 + threadIdx.x;
  if (i >= 1536 * 320) return;
  float x = (float)xi_h[i] + (float)xi_l[i];
  float p = x * (w1[0] + x * (w2[0] + x * (w3[0] + x * w4[0])));
  _Float16 h, l; split_f16(p, h, l);
  xo_h[i] = h; xo_l[i] = l;
}

// ---------------- projection: AD[row][0:100]=A+b1, [100:200]=D ----------------
__global__ __launch_bounds__(512) void proj_kernel(
    const _Float16* __restrict__ p_h, const _Float16* __restrict__ p_l,
    const _Float16* __restrict__ wpr_f,
    const float* __restrict__ b1cat,
    float* __restrict__ AD)   // [1536][256]
{
  const int t = blockIdx.x;
  const int tid = threadIdx.x, wv = tid >> 6, lane = tid & 63;
  const int lrow = lane & 15, lgrp = lane >> 4;
  float4v acc[2] = {{0.f, 0.f, 0.f, 0.f}, {0.f, 0.f, 0.f, 0.f}};
  const size_t arow = ((size_t)t * 16 + lrow) * 320;
#pragma unroll
  for (int kc = 0; kc < 10; ++kc) {
    int co = 32 * kc + 4 * lgrp;
    half8 ah = cat44h(*(const half4*)(p_h + arow + co),
                      *(const half4*)(p_h + arow + co + 16));
    half8 al = cat44h(*(const half4*)(p_l + arow + co),
                      *(const half4*)(p_l + arow + co + 16));
#pragma unroll
    for (int tt = 0; tt < 2; ++tt) {
      int nt = 2 * wv + tt;
      size_t wo = ((size_t)(nt * 10 + kc) * 64 + lane) * 8;
      half8 bw = *(const half8*)(wpr_f + wo);
      acc[tt] = mfma16h(ah, bw, acc[tt]);
      acc[tt] = mfma16h(al, bw, acc[tt]);
    }
  }
#pragma unroll
  for (int tt = 0; tt < 2; ++tt) {
    int ko = 16 * (2 * wv + tt) + lrow;
    float bv = b1cat[ko];
#pragma unroll
    for (int jj = 0; jj < 4; ++jj)
      AD[((size_t)t * 16 + 4 * lgrp + jj) * 256 + ko] = acc[tt][jj] + bv;
  }
}

// ---------------- combine: out[lh][b][ld] = b2 + sum_k w2[k]*tanh(A+D) ----------------
__global__ __launch_bounds__(768) void combine_kernel(
    const float* __restrict__ AD, const float* __restrict__ w2v,
    const float* __restrict__ b2v, float* __restrict__ out)
{
  const int bb = blockIdx.x & 15, lt = blockIdx.x >> 4;
  const int tid = threadIdx.x;
  __shared__ float Dl[100 * 97];  // [k][ld], stride 97
  __shared__ float Al[100 * 9];   // [k][lh], stride 9
  __shared__ float w2s[100];
  for (int i = tid; i < 96 * 32; i += 768) {
    int ld = i >> 5, f4 = i & 31;
    if (f4 < 25) {
      float4v v = *(const float4v*)(AD + ((size_t)ld * 16 + bb) * 256 + 100 + 4 * f4);
      int k0 = 4 * f4;
      Dl[(k0 + 0) * 97 + ld] = v[0];
      Dl[(k0 + 1) * 97 + ld] = v[1];
      Dl[(k0 + 2) * 97 + ld] = v[2];
      Dl[(k0 + 3) * 97 + ld] = v[3];
    }
  }
  for (int i = tid; i < 8 * 32; i += 768) {
    int lh = i >> 5, f4 = i & 31;
    if (f4 < 25) {
      int lseq = lt * 8 + lh;
      float4v v = *(const float4v*)(AD + ((size_t)lseq * 16 + bb) * 256 + 4 * f4);
      int k0 = 4 * f4;
      Al[(k0 + 0) * 9 + lh] = v[0];
      Al[(k0 + 1) * 9 + lh] = v[1];
      Al[(k0 + 2) * 9 + lh] = v[2];
      Al[(k0 + 3) * 9 + lh] = v[3];
    }
  }
  if (tid < 100) w2s[tid] = w2v[tid];
  __syncthreads();
  int lh = tid / 96, ld = tid - 96 * lh;
  float s = 0.f;
#pragma unroll 4
  for (int k = 0; k < 100; ++k) {
    float x = Al[k * 9 + lh] + Dl[k * 97 + ld];
    s += w2s[k] * fast_tanh(x);
  }
  out[((size_t)(lt * 8 + lh) * 16 + bb) * 96 + ld] = s + b2v[0];
}

// ---------------- host ----------------
extern "C" void kernel_launch(void* const* d_in, const int* in_sizes, int n_in,
                              void* d_out, int out_size, void* d_ws, size_t ws_size,
                              hipStream_t stream)
{
  const int*   widx = (const int*)d_in[0];
  const int*   pidx = (const int*)d_in[1];
  const float* wemb = (const float*)d_in[3];
  const float* temb = (const float*)d_in[4];
  const float* Wih0 = (const float*)d_in[5];
  const float* WihR = (const float*)d_in[6];
  const float* Whh  = (const float*)d_in[7];
  const float* bih  = (const float*)d_in[8];
  const float* bhh  = (const float*)d_in[9];
  const float* w1   = (const float*)d_in[10];
  const float* w2   = (const float*)d_in[11];
  const float* w3   = (const float*)d_in[12];
  const float* w4   = (const float*)d_in[13];
  const float* w1m  = (const float*)d_in[14];
  const float* b1v  = (const float*)d_in[15];
  const float* w2m  = (const float*)d_in[16];
  const float* b2v  = (const float*)d_in[17];
  float* out = (float*)d_out;

  char* ws = (char*)d_ws;
  size_t off = 0;
  auto alloc = [&](size_t bytes) -> char* {
    char* p = ws + off;
    off = (off + bytes + 255) & ~(size_t)255;
    return p;
  };
  _Float16* WHH_F = (_Float16*)alloc(819200ull * 2);
  _Float16* WIH_F = (_Float16*)alloc(1433600ull * 2);
  _Float16* WPR_F = (_Float16*)alloc(81920ull * 2);
  float* BSUM = (float*)alloc(5120ull * 4);
  float* B1C  = (float*)alloc(256ull * 4);
  _Float16* XA_H = (_Float16*)alloc(491520ull * 2);
  _Float16* XA_L = (_Float16*)alloc(491520ull * 2);
  _Float16* XB_H = (_Float16*)alloc(491520ull * 2);
  _Float16* XB_L = (_Float16*)alloc(491520ull * 2);
  float* PRE = (float*)alloc(1966080ull * 4);
  float* AD  = (float*)alloc(1536ull * 256 * 4);

  prep_kernel<<<512, 256, 0, stream>>>(Wih0, WihR, Whh, bih, bhh, w1m, b1v,
      WHH_F, WIH_F, WPR_F, BSUM, B1C);
  embed_kernel<<<1536, 320, 0, stream>>>(widx, pidx, wemb, temb,
      XA_H, XA_L, XB_H, XB_L);

  for (int layer = 0; layer < 4; ++layer) {
    const _Float16* xin_h = (layer & 1) ? XB_H : XA_H;
    const _Float16* xin_l = (layer & 1) ? XB_L : XA_L;
    _Float16* xo_h = (layer & 1) ? XA_H : XB_H;
    _Float16* xo_l = (layer & 1) ? XA_L : XB_L;
    const float* bsl = BSUM + layer * 2 * 640;
    if (layer == 0) {
      pregemm_kernel<5><<<dim3(96, 2), 512, 0, stream>>>(
          xin_h, xin_l, WIH_F, bsl, PRE);
    } else {
      size_t wo = 204800ull + (size_t)(layer - 1) * 409600ull;
      pregemm_kernel<10><<<dim3(96, 2), 512, 0, stream>>>(
          xin_h, xin_l, WIH_F + wo, bsl, PRE);
    }
    scan_kernel<<<2, 640, 0, stream>>>(PRE, WHH_F, xo_h, xo_l, layer);
  }
  // layer-3 output sits in XA; poly -> XB; proj -> AD; combine -> out
  poly_kernel<<<1920, 256, 0, stream>>>(XA_H, XA_L, XB_H, XB_L, w1, w2, w3, w4);
  proj_kernel<<<96, 512, 0, stream>>>(XB_H, XB_L, WPR_F, B1C, AD);
  combine_kernel<<<192, 768, 0, stream>>>(AD, w2m, b2v, out);
}

// Round 6
// 580.758 us; speedup vs baseline: 5.2476x; 1.4206x over previous
//
#include <hip/hip_runtime.h>

// ---------------- types / helpers ----------------
typedef __attribute__((ext_vector_type(8))) _Float16 half8;
typedef __attribute__((ext_vector_type(4))) _Float16 half4;
typedef __attribute__((ext_vector_type(4))) float float4v;

__device__ __forceinline__ float4v mfma16h(half8 a, half8 b, float4v c) {
  return __builtin_amdgcn_mfma_f32_16x16x32_f16(a, b, c, 0, 0, 0);
}

__device__ __forceinline__ half8 cat44h(half4 a, half4 b) {
  half8 r;
  r[0]=a[0]; r[1]=a[1]; r[2]=a[2]; r[3]=a[3];
  r[4]=b[0]; r[5]=b[1]; r[6]=b[2]; r[7]=b[3];
  return r;
}

__device__ __forceinline__ void split_f16(float x, _Float16& hi, _Float16& lo) {
  hi = (_Float16)x;                 // RNE
  lo = (_Float16)(x - (float)hi);
}

#define KLOG2E 1.442695041f
__device__ __forceinline__ float fast_tanh(float x) {
  float z = __builtin_amdgcn_exp2f(2.f * KLOG2E * x);
  return 1.f - 2.f * __builtin_amdgcn_rcpf(1.f + z);
}

// sizes: B=16 L=96 H=150 4H=600(pad 640) EMB=150(pad 160) 2H=300(pad 320)
// rows indexed row = t*16 + b
// fragment slot formula (same for A and B operands; permutation cancels):
//   k(lane,e) = 32*kc + 16*(e>>2) + 4*(lane>>4) + (e&3)
// GATE-QUAD permutation (Wih/Whh/bsum only): output tile nt = jg*4 + gate,
//   source row g_src = gate*150 + jg*16 + lrow  (jg = j/16).

// ---------------- prep: fp16 weight fragments, gate-quad permuted ----------
__global__ void prep_kernel(
    const float* __restrict__ Wih0,   // [2][600][150]
    const float* __restrict__ WihR,   // [3][2][600][300]
    const float* __restrict__ Whh,    // [4][2][600][150]
    const float* __restrict__ bih,    // [4][2][600]
    const float* __restrict__ bhh,    // [4][2][600]
    const float* __restrict__ w1m,    // [100][600]
    const float* __restrict__ b1v,    // [100]
    _Float16* __restrict__ whh_f,
    _Float16* __restrict__ wih_f,
    _Float16* __restrict__ wpr_f,
    float* __restrict__ bsum, float* __restrict__ b1cat)
{
  const int N_whh  = 8 * 40 * 5 * 512;   // 819200
  const int N_wih0 = 2 * 40 * 5 * 512;   // 204800
  const int N_wihr = 6 * 40 * 10 * 512;  // 1228800
  const int N_wpr  = 16 * 10 * 512;      // 81920
  const int N_bs   = 8 * 640;            // 5120
  const int total  = N_whh + N_wih0 + N_wihr + N_wpr + N_bs + 256;
  for (int i = blockIdx.x * blockDim.x + threadIdx.x; i < total;
       i += gridDim.x * blockDim.x) {
    int idx = i;
    if (idx < N_whh) {
      int e = idx & 7, lane = (idx >> 3) & 63, r = idx >> 9;
      int kc = r % 5; r /= 5; int nt = r % 40; int ld = r / 40;
      int jrow = (nt >> 2) * 16 + (lane & 15);
      int g = (nt & 3) * 150 + jrow;
      int k = 32 * kc + 16 * (e >> 2) + 4 * (lane >> 4) + (e & 3);
      float v = (jrow < 150 && k < 150) ? Whh[((size_t)ld * 600 + g) * 150 + k] : 0.f;
      whh_f[idx] = (_Float16)v;
      continue;
    }
    idx -= N_whh;
    if (idx < N_wih0) {
      int e = idx & 7, lane = (idx >> 3) & 63, r = idx >> 9;
      int kc = r % 5; r /= 5; int nt = r % 40; int dir = r / 40;
      int jrow = (nt >> 2) * 16 + (lane & 15);
      int g = (nt & 3) * 150 + jrow;
      int k = 32 * kc + 16 * (e >> 2) + 4 * (lane >> 4) + (e & 3);
      float v = (jrow < 150 && k < 150) ? Wih0[((size_t)dir * 600 + g) * 150 + k] : 0.f;
      wih_f[idx] = (_Float16)v;
      continue;
    }
    idx -= N_wih0;
    if (idx < N_wihr) {
      int e = idx & 7, lane = (idx >> 3) & 63, r = idx >> 9;
      int kc = r % 10; r /= 10; int nt = r % 40; int ld = r / 40;
      int jrow = (nt >> 2) * 16 + (lane & 15);
      int g = (nt & 3) * 150 + jrow;
      int k = 32 * kc + 16 * (e >> 2) + 4 * (lane >> 4) + (e & 3);
      float v = (jrow < 150 && k < 300) ? WihR[((size_t)ld * 600 + g) * 300 + k] : 0.f;
      wih_f[N_wih0 + idx] = (_Float16)v;
      continue;
    }
    idx -= N_wihr;
    if (idx < N_wpr) {
      int e = idx & 7, lane = (idx >> 3) & 63, r = idx >> 9;
      int kc = r % 10; int nt = r / 10;
      int ko = 16 * nt + (lane & 15);
      int k = 32 * kc + 16 * (e >> 2) + 4 * (lane >> 4) + (e & 3);
      float v = 0.f;
      if (k < 300) {
        if (ko < 100) v = w1m[(size_t)ko * 600 + k];
        else if (ko < 200) v = w1m[(size_t)(ko - 100) * 600 + 300 + k];
      }
      wpr_f[idx] = (_Float16)v;
      continue;
    }
    idx -= N_wpr;
    if (idx < N_bs) {
      int ld = idx / 640, gp = idx - 640 * ld;
      int nt = gp >> 4, lrow = gp & 15;
      int jrow = (nt >> 2) * 16 + lrow;
      int g = (nt & 3) * 150 + jrow;
      bsum[idx] = (jrow < 150) ? bih[ld * 600 + g] + bhh[ld * 600 + g] : 0.f;
      continue;
    }
    idx -= N_bs;
    b1cat[idx] = (idx < 100) ? b1v[idx] : ((idx < 200) ? b1v[idx - 100] : 0.f);
  }
}

// ---------------- embedding gather -> single fp16 ----------------
__global__ void embed_kernel(const int* __restrict__ widx, const int* __restrict__ pidx,
    const float* __restrict__ wemb, const float* __restrict__ temb,
    _Float16* __restrict__ xa, _Float16* __restrict__ xb)
{
  int row = blockIdx.x;       // t*16 + b
  int j = threadIdx.x;        // 0..319
  int b = row & 15, t = row >> 4;
  float v = 0.f;
  if (j < 100) v = wemb[(size_t)widx[b * 96 + t] * 100 + j];
  else if (j < 150) v = temb[(size_t)pidx[b * 96 + t] * 50 + (j - 100)];
  size_t o = (size_t)row * 320 + j;
  xa[o] = (_Float16)v;
  if (j >= 300) xb[o] = (_Float16)0.f;
}

// ---------------- pre-GEMM: pre[d][t][b][g'] = x @ Wih^T + b (permuted g') ----------
template <int KC>
__global__ __launch_bounds__(512) void pregemm_kernel(
    const _Float16* __restrict__ x_h,
    const _Float16* __restrict__ wih_f,
    const float* __restrict__ bsum_l,
    float* __restrict__ pre)            // [2][96][16][640]
{
  const int t = blockIdx.x, dir = blockIdx.y;
  const int tid = threadIdx.x, wv = tid >> 6, lane = tid & 63;
  const int lrow = lane & 15, lgrp = lane >> 4;
  const _Float16* wf = wih_f + (size_t)dir * 40 * KC * 512;
  float4v acc[5];
#pragma unroll
  for (int tt = 0; tt < 5; ++tt) acc[tt] = (float4v){0.f, 0.f, 0.f, 0.f};
  const size_t arow = ((size_t)t * 16 + lrow) * 320;
#pragma unroll
  for (int kc = 0; kc < KC; ++kc) {
    int co = 32 * kc + 4 * lgrp;
    half8 ah = cat44h(*(const half4*)(x_h + arow + co),
                      *(const half4*)(x_h + arow + co + 16));
#pragma unroll
    for (int tt = 0; tt < 5; ++tt) {
      int nt = 5 * wv + tt;
      const size_t wo = ((size_t)(nt * KC + kc) * 64 + lane) * 8;
      half8 bw = *(const half8*)(wf + wo);
      acc[tt] = mfma16h(ah, bw, acc[tt]);
    }
  }
  float* po = pre + ((size_t)dir * 96 + t) * 16 * 640;
  const float* bs = bsum_l + dir * 640;
#pragma unroll
  for (int tt = 0; tt < 5; ++tt) {
    int g = 16 * (5 * wv + tt) + lrow;
    float bv = bs[g];
#pragma unroll
    for (int jj = 0; jj < 4; ++jj)
      po[(size_t)(4 * lgrp + jj) * 640 + g] = acc[tt][jj] + bv;
  }
}

// ---------------- sequential LSTM scan: 10 waves, single-fp16 h ----------------
// wave w owns gate-quad tiles 4w..4w+3 -> acc[0..3][jj] = i,f,g,o of (b,j=16w+lrow).
// Single fp16 h: 20 MFMA/wave/step, 8 trans/cell, ONE barrier/step, dbuf h.
__global__ __launch_bounds__(640, 1) void scan_kernel(
    const float* __restrict__ pre,                 // [2][96][16][640] (g' permuted)
    const _Float16* __restrict__ whh_f,
    _Float16* __restrict__ xo,                     // [1536][320]
    int layer)
{
  const int dir = blockIdx.x;
  const int tid = threadIdx.x, wv = tid >> 6, lane = tid & 63;
  const int lrow = lane & 15, lgrp = lane >> 4;

  // h in MFMA A-fragment order: pos = b*168 + kc*32 + q*8 + e   (q = lane>>4)
  __shared__ __align__(16) _Float16 hb[2][16 * 168];

  for (int i = tid; i < 2 * 16 * 168; i += 640)
    (&hb[0][0])[i] = (_Float16)0.f;

  // Whh fragments resident: 4 gate-quad tiles x 5 kc per wave (40 VGPR)
  const _Float16* b_base = whh_f + (size_t)(layer * 2 + dir) * 40 * 5 * 512;
  half8 Bw[4][5];
#pragma unroll
  for (int tt = 0; tt < 4; ++tt)
#pragma unroll
    for (int kc = 0; kc < 5; ++kc) {
      size_t o = ((size_t)((4 * wv + tt) * 5 + kc) * 64 + lane) * 8;
      Bw[tt][kc] = *(const half8*)(b_base + o);
    }

  float cst[4] = {0.f, 0.f, 0.f, 0.f};
  const int j = 16 * wv + lrow;          // this thread's cell column
  const int kcj = j >> 5, wj = j & 31;   // h-fragment slot for (b, j)
  const int hoff = kcj * 32 + ((wj >> 2) & 3) * 8 + (wj >> 4) * 4 + (wj & 3);
  const bool jok = (j < 150);

  const int t0 = dir ? 95 : 0;
  const long pinc = dir ? -(16 * 640) : (16 * 640);
  const long xinc = dir ? -(16 * 320) : (16 * 320);
  const float* pt = pre + (size_t)dir * 96 * 16 * 640 + (size_t)t0 * 16 * 640;
  _Float16* xop = xo + ((size_t)t0 * 16 + 4 * lgrp) * 320 + dir * 150 + j;

  // prefetch PRE for step 0
  float4v pf[4];
#pragma unroll
  for (int tt = 0; tt < 4; ++tt) {
    int gp = 16 * (4 * wv + tt) + lrow;
#pragma unroll
    for (int jj = 0; jj < 4; ++jj)
      pf[tt][jj] = pt[(size_t)(4 * lgrp + jj) * 640 + gp];
  }
  __syncthreads();

#pragma unroll 1
  for (int step = 0; step < 96; ++step) {
    float4v acc[4];
#pragma unroll
    for (int tt = 0; tt < 4; ++tt) acc[tt] = pf[tt];

    const _Float16* hh = hb[step & 1];
#pragma unroll
    for (int kc = 0; kc < 5; ++kc) {
      const int ao = lrow * 168 + kc * 32 + lgrp * 8;
      half8 ah = *(const half8*)(hh + ao);
#pragma unroll
      for (int tt = 0; tt < 4; ++tt)
        acc[tt] = mfma16h(ah, Bw[tt][kc], acc[tt]);
    }

    // prefetch next step's PRE (hidden under state phase)
    pt += pinc;
    if (step < 95) {
#pragma unroll
      for (int tt = 0; tt < 4; ++tt) {
        int gp = 16 * (4 * wv + tt) + lrow;
#pragma unroll
        for (int jj = 0; jj < 4; ++jj)
          pf[tt][jj] = pt[(size_t)(4 * lgrp + jj) * 640 + gp];
      }
    }

    // state phase: gates thread-local (acc[0..3] = i,f,g,o preacts)
    // 8 trans/cell: 5 exp2 + 3 rcp (shared denominators for i*g and o*tanh(c))
    _Float16* nhh = hb[(step + 1) & 1];
#pragma unroll
    for (int jj = 0; jj < 4; ++jj) {
      float zi = __builtin_amdgcn_exp2f(-KLOG2E * acc[0][jj]);
      float zf = __builtin_amdgcn_exp2f(-KLOG2E * acc[1][jj]);
      float zg = __builtin_amdgcn_exp2f(2.f * KLOG2E * acc[2][jj]);
      float zo = __builtin_amdgcn_exp2f(-KLOG2E * acc[3][jj]);
      float rf = __builtin_amdgcn_rcpf(1.f + zf);
      float r2 = __builtin_amdgcn_rcpf((1.f + zi) * (zg + 1.f));
      float c = cst[jj] * rf + (zg - 1.f) * r2;
      cst[jj] = c;
      float zc = __builtin_amdgcn_exp2f(2.f * KLOG2E * c);
      float r3 = __builtin_amdgcn_rcpf((1.f + zo) * (zc + 1.f));
      float h = (zc - 1.f) * r3;
      _Float16 hv = (_Float16)h;
      nhh[(4 * lgrp + jj) * 168 + hoff] = hv;
      if (jok) xop[jj * 320] = hv;
    }
    xop += xinc;
    __syncthreads();
  }
}

// ---------------- elementwise degree-4 polynomial: fp16 x -> hi/lo p ----------------
__global__ void poly_kernel(const _Float16* __restrict__ xi,
    _Float16* __restrict__ po_h, _Float16* __restrict__ po_l,
    const float* __restrict__ w1, const float* __restrict__ w2,
    const float* __restrict__ w3, const float* __restrict__ w4)
{
  int i = blockIdx.x * 256 + threadIdx.x;
  if (i >= 1536 * 320) return;
  float x = (float)xi[i];
  float p = x * (w1[0] + x * (w2[0] + x * (w3[0] + x * w4[0])));
  _Float16 h, l; split_f16(p, h, l);
  po_h[i] = h; po_l[i] = l;
}

// ---------------- projection: AD[row][0:100]=A+b1, [100:200]=D ----------------
__global__ __launch_bounds__(512) void proj_kernel(
    const _Float16* __restrict__ p_h, const _Float16* __restrict__ p_l,
    const _Float16* __restrict__ wpr_f,
    const float* __restrict__ b1cat,
    float* __restrict__ AD)   // [1536][256]
{
  const int t = blockIdx.x;
  const int tid = threadIdx.x, wv = tid >> 6, lane = tid & 63;
  const int lrow = lane & 15, lgrp = lane >> 4;
  float4v acc[2] = {{0.f, 0.f, 0.f, 0.f}, {0.f, 0.f, 0.f, 0.f}};
  const size_t arow = ((size_t)t * 16 + lrow) * 320;
#pragma unroll
  for (int kc = 0; kc < 10; ++kc) {
    int co = 32 * kc + 4 * lgrp;
    half8 ah = cat44h(*(const half4*)(p_h + arow + co),
                      *(const half4*)(p_h + arow + co + 16));
    half8 al = cat44h(*(const half4*)(p_l + arow + co),
                      *(const half4*)(p_l + arow + co + 16));
#pragma unroll
    for (int tt = 0; tt < 2; ++tt) {
      int nt = 2 * wv + tt;
      size_t wo = ((size_t)(nt * 10 + kc) * 64 + lane) * 8;
      half8 bw = *(const half8*)(wpr_f + wo);
      acc[tt] = mfma16h(ah, bw, acc[tt]);
      acc[tt] = mfma16h(al, bw, acc[tt]);
    }
  }
#pragma unroll
  for (int tt = 0; tt < 2; ++tt) {
    int ko = 16 * (2 * wv + tt) + lrow;
    float bv = b1cat[ko];
#pragma unroll
    for (int jj = 0; jj < 4; ++jj)
      AD[((size_t)t * 16 + 4 * lgrp + jj) * 256 + ko] = acc[tt][jj] + bv;
  }
}

// ---------------- combine: out[lh][b][ld] = b2 + sum_k w2[k]*tanh(A+D) ----------------
__global__ __launch_bounds__(768) void combine_kernel(
    const float* __restrict__ AD, const float* __restrict__ w2v,
    const float* __restrict__ b2v, float* __restrict__ out)
{
  const int bb = blockIdx.x & 15, lt = blockIdx.x >> 4;
  const int tid = threadIdx.x;
  __shared__ float Dl[100 * 97];  // [k][ld], stride 97
  __shared__ float Al[100 * 9];   // [k][lh], stride 9
  __shared__ float w2s[100];
  for (int i = tid; i < 96 * 32; i += 768) {
    int ld = i >> 5, f4 = i & 31;
    if (f4 < 25) {
      float4v v = *(const float4v*)(AD + ((size_t)ld * 16 + bb) * 256 + 100 + 4 * f4);
      int k0 = 4 * f4;
      Dl[(k0 + 0) * 97 + ld] = v[0];
      Dl[(k0 + 1) * 97 + ld] = v[1];
      Dl[(k0 + 2) * 97 + ld] = v[2];
      Dl[(k0 + 3) * 97 + ld] = v[3];
    }
  }
  for (int i = tid; i < 8 * 32; i += 768) {
    int lh = i >> 5, f4 = i & 31;
    if (f4 < 25) {
      int lseq = lt * 8 + lh;
      float4v v = *(const float4v*)(AD + ((size_t)lseq * 16 + bb) * 256 + 4 * f4);
      int k0 = 4 * f4;
      Al[(k0 + 0) * 9 + lh] = v[0];
      Al[(k0 + 1) * 9 + lh] = v[1];
      Al[(k0 + 2) * 9 + lh] = v[2];
      Al[(k0 + 3) * 9 + lh] = v[3];
    }
  }
  if (tid < 100) w2s[tid] = w2v[tid];
  __syncthreads();
  int lh = tid / 96, ld = tid - 96 * lh;
  float s = 0.f;
#pragma unroll 4
  for (int k = 0; k < 100; ++k) {
    float x = Al[k * 9 + lh] + Dl[k * 97 + ld];
    s += w2s[k] * fast_tanh(x);
  }
  out[((size_t)(lt * 8 + lh) * 16 + bb) * 96 + ld] = s + b2v[0];
}

// ---------------- host ----------------
extern "C" void kernel_launch(void* const* d_in, const int* in_sizes, int n_in,
                              void* d_out, int out_size, void* d_ws, size_t ws_size,
                              hipStream_t stream)
{
  const int*   widx = (const int*)d_in[0];
  const int*   pidx = (const int*)d_in[1];
  const float* wemb = (const float*)d_in[3];
  const float* temb = (const float*)d_in[4];
  const float* Wih0 = (const float*)d_in[5];
  const float* WihR = (const float*)d_in[6];
  const float* Whh  = (const float*)d_in[7];
  const float* bih  = (const float*)d_in[8];
  const float* bhh  = (const float*)d_in[9];
  const float* w1   = (const float*)d_in[10];
  const float* w2   = (const float*)d_in[11];
  const float* w3   = (const float*)d_in[12];
  const float* w4   = (const float*)d_in[13];
  const float* w1m  = (const float*)d_in[14];
  const float* b1v  = (const float*)d_in[15];
  const float* w2m  = (const float*)d_in[16];
  const float* b2v  = (const float*)d_in[17];
  float* out = (float*)d_out;

  char* ws = (char*)d_ws;
  size_t off = 0;
  auto alloc = [&](size_t bytes) -> char* {
    char* p = ws + off;
    off = (off + bytes + 255) & ~(size_t)255;
    return p;
  };
  _Float16* WHH_F = (_Float16*)alloc(819200ull * 2);
  _Float16* WIH_F = (_Float16*)alloc(1433600ull * 2);
  _Float16* WPR_F = (_Float16*)alloc(81920ull * 2);
  float* BSUM = (float*)alloc(5120ull * 4);
  float* B1C  = (float*)alloc(256ull * 4);
  _Float16* XA = (_Float16*)alloc(491520ull * 2);
  _Float16* XB = (_Float16*)alloc(491520ull * 2);
  _Float16* PH = (_Float16*)alloc(491520ull * 2);
  _Float16* PL = (_Float16*)alloc(491520ull * 2);
  float* PRE = (float*)alloc(1966080ull * 4);
  float* AD  = (float*)alloc(1536ull * 256 * 4);

  prep_kernel<<<512, 256, 0, stream>>>(Wih0, WihR, Whh, bih, bhh, w1m, b1v,
      WHH_F, WIH_F, WPR_F, BSUM, B1C);
  embed_kernel<<<1536, 320, 0, stream>>>(widx, pidx, wemb, temb, XA, XB);

  for (int layer = 0; layer < 4; ++layer) {
    const _Float16* xin = (layer & 1) ? XB : XA;
    _Float16* xout = (layer & 1) ? XA : XB;
    const float* bsl = BSUM + layer * 2 * 640;
    if (layer == 0) {
      pregemm_kernel<5><<<dim3(96, 2), 512, 0, stream>>>(xin, WIH_F, bsl, PRE);
    } else {
      size_t wo = 204800ull + (size_t)(layer - 1) * 409600ull;
      pregemm_kernel<10><<<dim3(96, 2), 512, 0, stream>>>(xin, WIH_F + wo, bsl, PRE);
    }
    scan_kernel<<<2, 640, 0, stream>>>(PRE, WHH_F, xout, layer);
  }
  // layer-3 output sits in XA; poly -> PH/PL; proj -> AD; combine -> out
  poly_kernel<<<1920, 256, 0, stream>>>(XA, PH, PL, w1, w2, w3, w4);
  proj_kernel<<<96, 512, 0, stream>>>(PH, PL, WPR_F, B1C, AD);
  combine_kernel<<<192, 768, 0, stream>>>(AD, w2m, b2v, out);
}

// Round 7
// 543.653 us; speedup vs baseline: 5.6057x; 1.0682x over previous
//
#include <hip/hip_runtime.h>

// ---------------- types / helpers ----------------
typedef __attribute__((ext_vector_type(8))) _Float16 half8;
typedef __attribute__((ext_vector_type(4))) _Float16 half4;
typedef __attribute__((ext_vector_type(4))) float float4v;

__device__ __forceinline__ float4v mfma16h(half8 a, half8 b, float4v c) {
  return __builtin_amdgcn_mfma_f32_16x16x32_f16(a, b, c, 0, 0, 0);
}

__device__ __forceinline__ half8 cat44h(half4 a, half4 b) {
  half8 r;
  r[0]=a[0]; r[1]=a[1]; r[2]=a[2]; r[3]=a[3];
  r[4]=b[0]; r[5]=b[1]; r[6]=b[2]; r[7]=b[3];
  return r;
}

__device__ __forceinline__ void split_f16(float x, _Float16& hi, _Float16& lo) {
  hi = (_Float16)x;                 // RNE
  lo = (_Float16)(x - (float)hi);
}

#define KLOG2E 1.442695041f
__device__ __forceinline__ float fast_tanh(float x) {
  float z = __builtin_amdgcn_exp2f(2.f * KLOG2E * x);
  return 1.f - 2.f * __builtin_amdgcn_rcpf(1.f + z);
}

// sizes: B=16 L=96 H=150 4H=600(pad 640) EMB=150(pad 160) 2H=300(pad 320)
// fragment slot formula (same for A and B operands; permutation cancels):
//   k(lane,e) = 32*kc + 16*(e>>2) + 4*(lane>>4) + (e&3)
// GATE-QUAD permutation: tile nt = jg*4 + gate, source row g = gate*150 + jg*16 + lrow.
// GATE-SCALE folding: rows of Wih/Whh/bsum pre-scaled by (-log2e) for i,f,o and
//   (+2log2e) for g, so scan's state phase is exp2(acc) directly.
// PRE layout: [dir][t][tid(640)][16] -- each scan thread's 16 preacts contiguous.

// ---------------- prep: fp16 weight fragments, permuted + scaled ----------
__global__ void prep_kernel(
    const float* __restrict__ Wih0,   // [2][600][150]
    const float* __restrict__ WihR,   // [3][2][600][300]
    const float* __restrict__ Whh,    // [4][2][600][150]
    const float* __restrict__ bih,    // [4][2][600]
    const float* __restrict__ bhh,    // [4][2][600]
    const float* __restrict__ w1m,    // [100][600]
    const float* __restrict__ b1v,    // [100]
    _Float16* __restrict__ whh_f,
    _Float16* __restrict__ wih_f,
    _Float16* __restrict__ wpr_f,
    float* __restrict__ bsum, float* __restrict__ b1cat)
{
  const int N_whh  = 8 * 40 * 5 * 512;   // 819200
  const int N_wih0 = 2 * 40 * 5 * 512;   // 204800
  const int N_wihr = 6 * 40 * 10 * 512;  // 1228800
  const int N_wpr  = 16 * 10 * 512;      // 81920
  const int N_bs   = 8 * 640;            // 5120
  const int total  = N_whh + N_wih0 + N_wihr + N_wpr + N_bs + 256;
  for (int i = blockIdx.x * blockDim.x + threadIdx.x; i < total;
       i += gridDim.x * blockDim.x) {
    int idx = i;
    if (idx < N_whh) {
      int e = idx & 7, lane = (idx >> 3) & 63, r = idx >> 9;
      int kc = r % 5; r /= 5; int nt = r % 40; int ld = r / 40;
      int jrow = (nt >> 2) * 16 + (lane & 15);
      int g = (nt & 3) * 150 + jrow;
      int k = 32 * kc + 16 * (e >> 2) + 4 * (lane >> 4) + (e & 3);
      float v = (jrow < 150 && k < 150) ? Whh[((size_t)ld * 600 + g) * 150 + k] : 0.f;
      v *= ((nt & 3) == 2) ? (2.f * KLOG2E) : (-KLOG2E);
      whh_f[idx] = (_Float16)v;
      continue;
    }
    idx -= N_whh;
    if (idx < N_wih0) {
      int e = idx & 7, lane = (idx >> 3) & 63, r = idx >> 9;
      int kc = r % 5; r /= 5; int nt = r % 40; int dir = r / 40;
      int jrow = (nt >> 2) * 16 + (lane & 15);
      int g = (nt & 3) * 150 + jrow;
      int k = 32 * kc + 16 * (e >> 2) + 4 * (lane >> 4) + (e & 3);
      float v = (jrow < 150 && k < 150) ? Wih0[((size_t)dir * 600 + g) * 150 + k] : 0.f;
      v *= ((nt & 3) == 2) ? (2.f * KLOG2E) : (-KLOG2E);
      wih_f[idx] = (_Float16)v;
      continue;
    }
    idx -= N_wih0;
    if (idx < N_wihr) {
      int e = idx & 7, lane = (idx >> 3) & 63, r = idx >> 9;
      int kc = r % 10; r /= 10; int nt = r % 40; int ld = r / 40;
      int jrow = (nt >> 2) * 16 + (lane & 15);
      int g = (nt & 3) * 150 + jrow;
      int k = 32 * kc + 16 * (e >> 2) + 4 * (lane >> 4) + (e & 3);
      float v = (jrow < 150 && k < 300) ? WihR[((size_t)ld * 600 + g) * 300 + k] : 0.f;
      v *= ((nt & 3) == 2) ? (2.f * KLOG2E) : (-KLOG2E);
      wih_f[N_wih0 + idx] = (_Float16)v;
      continue;
    }
    idx -= N_wihr;
    if (idx < N_wpr) {
      int e = idx & 7, lane = (idx >> 3) & 63, r = idx >> 9;
      int kc = r % 10; int nt = r / 10;
      int ko = 16 * nt + (lane & 15);
      int k = 32 * kc + 16 * (e >> 2) + 4 * (lane >> 4) + (e & 3);
      float v = 0.f;
      if (k < 300) {
        if (ko < 100) v = w1m[(size_t)ko * 600 + k];
        else if (ko < 200) v = w1m[(size_t)(ko - 100) * 600 + 300 + k];
      }
      wpr_f[idx] = (_Float16)v;
      continue;
    }
    idx -= N_wpr;
    if (idx < N_bs) {
      int ld = idx / 640, gp = idx - 640 * ld;
      int nt = gp >> 4, lrow = gp & 15;
      int jrow = (nt >> 2) * 16 + lrow;
      int g = (nt & 3) * 150 + jrow;
      float v = (jrow < 150) ? bih[ld * 600 + g] + bhh[ld * 600 + g] : 0.f;
      v *= ((nt & 3) == 2) ? (2.f * KLOG2E) : (-KLOG2E);
      bsum[idx] = v;
      continue;
    }
    idx -= N_bs;
    b1cat[idx] = (idx < 100) ? b1v[idx] : ((idx < 200) ? b1v[idx - 100] : 0.f);
  }
}

// ---------------- embedding gather -> single fp16 ----------------
__global__ void embed_kernel(const int* __restrict__ widx, const int* __restrict__ pidx,
    const float* __restrict__ wemb, const float* __restrict__ temb,
    _Float16* __restrict__ xa, _Float16* __restrict__ xb)
{
  int row = blockIdx.x;       // t*16 + b
  int j = threadIdx.x;        // 0..319
  int b = row & 15, t = row >> 4;
  float v = 0.f;
  if (j < 100) v = wemb[(size_t)widx[b * 96 + t] * 100 + j];
  else if (j < 150) v = temb[(size_t)pidx[b * 96 + t] * 50 + (j - 100)];
  size_t o = (size_t)row * 320 + j;
  xa[o] = (_Float16)v;
  if (j >= 300) xb[o] = (_Float16)0.f;
}

// ---------------- pre-GEMM: writes scan-fragment-ordered PRE chunks ----------------
template <int KC>
__global__ __launch_bounds__(512) void pregemm_kernel(
    const _Float16* __restrict__ x_h,
    const _Float16* __restrict__ wih_f,
    const float* __restrict__ bsum_l,
    float* __restrict__ pre)            // [2][96][640][16]
{
  const int t = blockIdx.x, dir = blockIdx.y;
  const int tid = threadIdx.x, wv = tid >> 6, lane = tid & 63;
  const int lrow = lane & 15, lgrp = lane >> 4;
  const _Float16* wf = wih_f + (size_t)dir * 40 * KC * 512;
  float4v acc[5];
#pragma unroll
  for (int tt = 0; tt < 5; ++tt) acc[tt] = (float4v){0.f, 0.f, 0.f, 0.f};
  const size_t arow = ((size_t)t * 16 + lrow) * 320;
#pragma unroll
  for (int kc = 0; kc < KC; ++kc) {
    int co = 32 * kc + 4 * lgrp;
    half8 ah = cat44h(*(const half4*)(x_h + arow + co),
                      *(const half4*)(x_h + arow + co + 16));
#pragma unroll
    for (int tt = 0; tt < 5; ++tt) {
      int nt = 5 * wv + tt;
      const size_t wo = ((size_t)(nt * KC + kc) * 64 + lane) * 8;
      half8 bw = *(const half8*)(wf + wo);
      acc[tt] = mfma16h(ah, bw, acc[tt]);
    }
  }
  float* po = pre + (size_t)(dir * 96 + t) * 10240;
  const float* bs = bsum_l + dir * 640;
#pragma unroll
  for (int tt = 0; tt < 5; ++tt) {
    int nt = 5 * wv + tt;
    float bv = bs[16 * nt + lrow];
    float4v v;
#pragma unroll
    for (int jj = 0; jj < 4; ++jj) v[jj] = acc[tt][jj] + bv;
    int tid_s = (nt >> 2) * 64 + lgrp * 16 + lrow;   // scan-thread owner
    *(float4v*)(po + (size_t)tid_s * 16 + (nt & 3) * 4) = v;
  }
}

// ---------------- sequential LSTM scan: 10 waves, gates thread-local ----------------
// PRE chunks contiguous per thread (4x dwordx4), depth-2 prefetch (pfA/pfB),
// MFMA in place into prefetch regs, gate-scale folded, one barrier/step.
__global__ __launch_bounds__(640, 1) void scan_kernel(
    const float* __restrict__ pre,                 // [2][96][640][16]
    const _Float16* __restrict__ whh_f,
    _Float16* __restrict__ xo,                     // [1536][320]
    int layer)
{
  const int dir = blockIdx.x;
  const int tid = threadIdx.x, wv = tid >> 6, lane = tid & 63;
  const int lrow = lane & 15, lgrp = lane >> 4;

  // h in MFMA A-fragment order, row stride 172 (conflict-free ds_read_b128)
  __shared__ __align__(16) _Float16 hb[2][16 * 172];

  for (int i = tid; i < 2 * 16 * 172; i += 640)
    (&hb[0][0])[i] = (_Float16)0.f;

  // Whh fragments resident: 4 gate-quad tiles x 5 kc per wave (40 VGPR)
  const _Float16* b_base = whh_f + (size_t)(layer * 2 + dir) * 40 * 5 * 512;
  half8 Bw[4][5];
#pragma unroll
  for (int tt = 0; tt < 4; ++tt)
#pragma unroll
    for (int kc = 0; kc < 5; ++kc) {
      size_t o = ((size_t)((4 * wv + tt) * 5 + kc) * 64 + lane) * 8;
      Bw[tt][kc] = *(const half8*)(b_base + o);
    }

  float cst[4] = {0.f, 0.f, 0.f, 0.f};
  const int j = 16 * wv + lrow;          // this thread's cell column
  const int kcj = j >> 5, wj = j & 31;   // h-fragment slot for (b, j)
  const int hoff = kcj * 32 + ((wj >> 2) & 3) * 8 + (wj >> 4) * 4 + (wj & 3);
  const bool jok = (j < 150);

  const int t0 = dir ? 95 : 0;
  const long pincv = dir ? -2560 : 2560;           // float4v per t step
  const long xinc = dir ? -(16 * 320) : (16 * 320);
  const float4v* pc = (const float4v*)pre + ((size_t)(dir * 96 + t0) * 640 + tid) * 4;
  _Float16* xop = xo + ((size_t)t0 * 16 + 4 * lgrp) * 320 + dir * 150 + j;

  float4v pfA[4], pfB[4];
#pragma unroll
  for (int i = 0; i < 4; ++i) pfA[i] = pc[i];
  pc += pincv;
#pragma unroll
  for (int i = 0; i < 4; ++i) pfB[i] = pc[i];
  pc += pincv;
  __syncthreads();

#define SCAN_STEP(PF, HIN, HOUT)                                          \
  {                                                                       \
    _Pragma("unroll")                                                     \
    for (int kc = 0; kc < 5; ++kc) {                                      \
      const int ao = lrow * 172 + kc * 32 + lgrp * 8;                     \
      half8 ah = *(const half8*)((HIN) + ao);                             \
      _Pragma("unroll")                                                   \
      for (int tt = 0; tt < 4; ++tt)                                      \
        PF[tt] = mfma16h(ah, Bw[tt][kc], PF[tt]);                         \
    }                                                                     \
    _Pragma("unroll")                                                     \
    for (int jj = 0; jj < 4; ++jj) {                                      \
      float zi = __builtin_amdgcn_exp2f(PF[0][jj]);                       \
      float zf = __builtin_amdgcn_exp2f(PF[1][jj]);                       \
      float zg = __builtin_amdgcn_exp2f(PF[2][jj]);                       \
      float zo = __builtin_amdgcn_exp2f(PF[3][jj]);                       \
      float rf = __builtin_amdgcn_rcpf(1.f + zf);                         \
      float r2 = __builtin_amdgcn_rcpf((1.f + zi) * (zg + 1.f));          \
      float c = cst[jj] * rf + (zg - 1.f) * r2;                           \
      cst[jj] = c;                                                        \
      float zc = __builtin_amdgcn_exp2f(2.f * KLOG2E * c);                \
      float r3 = __builtin_amdgcn_rcpf((1.f + zo) * (zc + 1.f));          \
      float h = (zc - 1.f) * r3;                                          \
      _Float16 hv = (_Float16)h;                                          \
      (HOUT)[(4 * lgrp + jj) * 172 + hoff] = hv;                          \
      if (jok) xop[jj * 320] = hv;                                        \
    }                                                                     \
    _Pragma("unroll")                                                     \
    for (int i = 0; i < 4; ++i) PF[i] = pc[i];                            \
    pc += pincv;                                                          \
    xop += xinc;                                                          \
    __syncthreads();                                                      \
  }

#pragma unroll 1
  for (int s2 = 0; s2 < 48; ++s2) {
    SCAN_STEP(pfA, hb[0], hb[1]);
    SCAN_STEP(pfB, hb[1], hb[0]);
  }
#undef SCAN_STEP
}

// ---------------- elementwise degree-4 polynomial: fp16 x -> hi/lo p ----------------
__global__ void poly_kernel(const _Float16* __restrict__ xi,
    _Float16* __restrict__ po_h, _Float16* __restrict__ po_l,
    const float* __restrict__ w1, const float* __restrict__ w2,
    const float* __restrict__ w3, const float* __restrict__ w4)
{
  int i = blockIdx.x * 256 + threadIdx.x;
  if (i >= 1536 * 320) return;
  float x = (float)xi[i];
  float p = x * (w1[0] + x * (w2[0] + x * (w3[0] + x * w4[0])));
  _Float16 h, l; split_f16(p, h, l);
  po_h[i] = h; po_l[i] = l;
}

// ---------------- projection: AD[row][0:100]=A+b1, [100:200]=D ----------------
__global__ __launch_bounds__(512) void proj_kernel(
    const _Float16* __restrict__ p_h, const _Float16* __restrict__ p_l,
    const _Float16* __restrict__ wpr_f,
    const float* __restrict__ b1cat,
    float* __restrict__ AD)   // [1536][256]
{
  const int t = blockIdx.x;
  const int tid = threadIdx.x, wv = tid >> 6, lane = tid & 63;
  const int lrow = lane & 15, lgrp = lane >> 4;
  float4v acc[2] = {{0.f, 0.f, 0.f, 0.f}, {0.f, 0.f, 0.f, 0.f}};
  const size_t arow = ((size_t)t * 16 + lrow) * 320;
#pragma unroll
  for (int kc = 0; kc < 10; ++kc) {
    int co = 32 * kc + 4 * lgrp;
    half8 ah = cat44h(*(const half4*)(p_h + arow + co),
                      *(const half4*)(p_h + arow + co + 16));
    half8 al = cat44h(*(const half4*)(p_l + arow + co),
                      *(const half4*)(p_l + arow + co + 16));
#pragma unroll
    for (int tt = 0; tt < 2; ++tt) {
      int nt = 2 * wv + tt;
      size_t wo = ((size_t)(nt * 10 + kc) * 64 + lane) * 8;
      half8 bw = *(const half8*)(wpr_f + wo);
      acc[tt] = mfma16h(ah, bw, acc[tt]);
      acc[tt] = mfma16h(al, bw, acc[tt]);
    }
  }
#pragma unroll
  for (int tt = 0; tt < 2; ++tt) {
    int ko = 16 * (2 * wv + tt) + lrow;
    float bv = b1cat[ko];
#pragma unroll
    for (int jj = 0; jj < 4; ++jj)
      AD[((size_t)t * 16 + 4 * lgrp + jj) * 256 + ko] = acc[tt][jj] + bv;
  }
}

// ---------------- combine: out[lh][b][ld] = b2 + sum_k w2[k]*tanh(A+D) ----------------
__global__ __launch_bounds__(768) void combine_kernel(
    const float* __restrict__ AD, const float* __restrict__ w2v,
    const float* __restrict__ b2v, float* __restrict__ out)
{
  const int bb = blockIdx.x & 15, lt = blockIdx.x >> 4;
  const int tid = threadIdx.x;
  __shared__ float Dl[100 * 97];  // [k][ld], stride 97
  __shared__ float Al[100 * 9];   // [k][lh], stride 9
  __shared__ float w2s[100];
  for (int i = tid; i < 96 * 32; i += 768) {
    int ld = i >> 5, f4 = i & 31;
    if (f4 < 25) {
      float4v v = *(const float4v*)(AD + ((size_t)ld * 16 + bb) * 256 + 100 + 4 * f4);
      int k0 = 4 * f4;
      Dl[(k0 + 0) * 97 + ld] = v[0];
      Dl[(k0 + 1) * 97 + ld] = v[1];
      Dl[(k0 + 2) * 97 + ld] = v[2];
      Dl[(k0 + 3) * 97 + ld] = v[3];
    }
  }
  for (int i = tid; i < 8 * 32; i += 768) {
    int lh = i >> 5, f4 = i & 31;
    if (f4 < 25) {
      int lseq = lt * 8 + lh;
      float4v v = *(const float4v*)(AD + ((size_t)lseq * 16 + bb) * 256 + 4 * f4);
      int k0 = 4 * f4;
      Al[(k0 + 0) * 9 + lh] = v[0];
      Al[(k0 + 1) * 9 + lh] = v[1];
      Al[(k0 + 2) * 9 + lh] = v[2];
      Al[(k0 + 3) * 9 + lh] = v[3];
    }
  }
  if (tid < 100) w2s[tid] = w2v[tid];
  __syncthreads();
  int lh = tid / 96, ld = tid - 96 * lh;
  float s = 0.f;
#pragma unroll 4
  for (int k = 0; k < 100; ++k) {
    float x = Al[k * 9 + lh] + Dl[k * 97 + ld];
    s += w2s[k] * fast_tanh(x);
  }
  out[((size_t)(lt * 8 + lh) * 16 + bb) * 96 + ld] = s + b2v[0];
}

// ---------------- host ----------------
extern "C" void kernel_launch(void* const* d_in, const int* in_sizes, int n_in,
                              void* d_out, int out_size, void* d_ws, size_t ws_size,
                              hipStream_t stream)
{
  const int*   widx = (const int*)d_in[0];
  const int*   pidx = (const int*)d_in[1];
  const float* wemb = (const float*)d_in[3];
  const float* temb = (const float*)d_in[4];
  const float* Wih0 = (const float*)d_in[5];
  const float* WihR = (const float*)d_in[6];
  const float* Whh  = (const float*)d_in[7];
  const float* bih  = (const float*)d_in[8];
  const float* bhh  = (const float*)d_in[9];
  const float* w1   = (const float*)d_in[10];
  const float* w2   = (const float*)d_in[11];
  const float* w3   = (const float*)d_in[12];
  const float* w4   = (const float*)d_in[13];
  const float* w1m  = (const float*)d_in[14];
  const float* b1v  = (const float*)d_in[15];
  const float* w2m  = (const float*)d_in[16];
  const float* b2v  = (const float*)d_in[17];
  float* out = (float*)d_out;

  char* ws = (char*)d_ws;
  size_t off = 0;
  auto alloc = [&](size_t bytes) -> char* {
    char* p = ws + off;
    off = (off + bytes + 255) & ~(size_t)255;
    return p;
  };
  _Float16* WHH_F = (_Float16*)alloc(819200ull * 2);
  _Float16* WIH_F = (_Float16*)alloc(1433600ull * 2);
  _Float16* WPR_F = (_Float16*)alloc(81920ull * 2);
  float* BSUM = (float*)alloc(5120ull * 4);
  float* B1C  = (float*)alloc(256ull * 4);
  _Float16* XA = (_Float16*)alloc(491520ull * 2);
  _Float16* XB = (_Float16*)alloc(491520ull * 2);
  _Float16* PH = (_Float16*)alloc(491520ull * 2);
  _Float16* PL = (_Float16*)alloc(491520ull * 2);
  float* PRE = (float*)alloc(1966080ull * 4);
  float* AD  = (float*)alloc(1536ull * 256 * 4);

  prep_kernel<<<512, 256, 0, stream>>>(Wih0, WihR, Whh, bih, bhh, w1m, b1v,
      WHH_F, WIH_F, WPR_F, BSUM, B1C);
  embed_kernel<<<1536, 320, 0, stream>>>(widx, pidx, wemb, temb, XA, XB);

  for (int layer = 0; layer < 4; ++layer) {
    const _Float16* xin = (layer & 1) ? XB : XA;
    _Float16* xout = (layer & 1) ? XA : XB;
    const float* bsl = BSUM + layer * 2 * 640;
    if (layer == 0) {
      pregemm_kernel<5><<<dim3(96, 2), 512, 0, stream>>>(xin, WIH_F, bsl, PRE);
    } else {
      size_t wo = 204800ull + (size_t)(layer - 1) * 409600ull;
      pregemm_kernel<10><<<dim3(96, 2), 512, 0, stream>>>(xin, WIH_F + wo, bsl, PRE);
    }
    scan_kernel<<<2, 640, 0, stream>>>(PRE, WHH_F, xout, layer);
  }
  // layer-3 output sits in XA; poly -> PH/PL; proj -> AD; combine -> out
  poly_kernel<<<1920, 256, 0, stream>>>(XA, PH, PL, w1, w2, w3, w4);
  proj_kernel<<<96, 512, 0, stream>>>(PH, PL, WPR_F, B1C, AD);
  combine_kernel<<<192, 768, 0, stream>>>(AD, w2m, b2v, out);
}

// Round 8
// 529.245 us; speedup vs baseline: 5.7584x; 1.0272x over previous
//
#include <hip/hip_runtime.h>

// ---------------- types / helpers ----------------
typedef __attribute__((ext_vector_type(8))) _Float16 half8;
typedef __attribute__((ext_vector_type(4))) _Float16 half4;
typedef __attribute__((ext_vector_type(4))) float float4v;

__device__ __forceinline__ float4v mfma16h(half8 a, half8 b, float4v c) {
  return __builtin_amdgcn_mfma_f32_16x16x32_f16(a, b, c, 0, 0, 0);
}

__device__ __forceinline__ half8 cat44h(half4 a, half4 b) {
  half8 r;
  r[0]=a[0]; r[1]=a[1]; r[2]=a[2]; r[3]=a[3];
  r[4]=b[0]; r[5]=b[1]; r[6]=b[2]; r[7]=b[3];
  return r;
}

__device__ __forceinline__ void split_f16(float x, _Float16& hi, _Float16& lo) {
  hi = (_Float16)x;                 // RNE
  lo = (_Float16)(x - (float)hi);
}

#define KLOG2E 1.442695041f
__device__ __forceinline__ float fast_tanh(float x) {
  float z = __builtin_amdgcn_exp2f(2.f * KLOG2E * x);
  return 1.f - 2.f * __builtin_amdgcn_rcpf(1.f + z);
}

// sizes: B=16 L=96 H=150 4H=600(pad 640) EMB=150(pad 160) 2H=300(pad 320)
// fragment slot formula (same for A and B operands; permutation cancels):
//   k(lane,e) = 32*kc + 16*(e>>2) + 4*(lane>>4) + (e&3)
// GATE-QUAD permutation: tile nt = jg*4 + gate, source row g = gate*150 + jg*16 + lrow.
// GATE-SCALE folding: rows pre-scaled by (-log2e) for i,f,o and (+2log2e) for g.
// PRE layout: [dir][t][tid(640)][16] -- each scan thread's 16 preacts contiguous.

// ---------------- prep: weight fragments + embedding gather (fused) ----------
__global__ void prep_kernel(
    const float* __restrict__ Wih0,   // [2][600][150]
    const float* __restrict__ WihR,   // [3][2][600][300]
    const float* __restrict__ Whh,    // [4][2][600][150]
    const float* __restrict__ bih,    // [4][2][600]
    const float* __restrict__ bhh,    // [4][2][600]
    const float* __restrict__ w1m,    // [100][600]
    const float* __restrict__ b1v,    // [100]
    const int* __restrict__ widx, const int* __restrict__ pidx,
    const float* __restrict__ wemb, const float* __restrict__ temb,
    _Float16* __restrict__ whh_f,
    _Float16* __restrict__ wih_f,
    _Float16* __restrict__ wpr_f,
    float* __restrict__ bsum, float* __restrict__ b1cat,
    _Float16* __restrict__ xa, _Float16* __restrict__ xb)
{
  const int N_whh  = 8 * 40 * 5 * 512;   // 819200
  const int N_wih0 = 2 * 40 * 5 * 512;   // 204800
  const int N_wihr = 6 * 40 * 10 * 512;  // 1228800
  const int N_wpr  = 16 * 10 * 512;      // 81920
  const int N_bs   = 8 * 640;            // 5120
  const int N_emb  = 1536 * 320;         // 491520
  const int total  = N_whh + N_wih0 + N_wihr + N_wpr + N_bs + 256 + N_emb;
  for (int i = blockIdx.x * blockDim.x + threadIdx.x; i < total;
       i += gridDim.x * blockDim.x) {
    int idx = i;
    if (idx < N_whh) {
      int e = idx & 7, lane = (idx >> 3) & 63, r = idx >> 9;
      int kc = r % 5; r /= 5; int nt = r % 40; int ld = r / 40;
      int jrow = (nt >> 2) * 16 + (lane & 15);
      int g = (nt & 3) * 150 + jrow;
      int k = 32 * kc + 16 * (e >> 2) + 4 * (lane >> 4) + (e & 3);
      float v = (jrow < 150 && k < 150) ? Whh[((size_t)ld * 600 + g) * 150 + k] : 0.f;
      v *= ((nt & 3) == 2) ? (2.f * KLOG2E) : (-KLOG2E);
      whh_f[idx] = (_Float16)v;
      continue;
    }
    idx -= N_whh;
    if (idx < N_wih0) {
      int e = idx & 7, lane = (idx >> 3) & 63, r = idx >> 9;
      int kc = r % 5; r /= 5; int nt = r % 40; int dir = r / 40;
      int jrow = (nt >> 2) * 16 + (lane & 15);
      int g = (nt & 3) * 150 + jrow;
      int k = 32 * kc + 16 * (e >> 2) + 4 * (lane >> 4) + (e & 3);
      float v = (jrow < 150 && k < 150) ? Wih0[((size_t)dir * 600 + g) * 150 + k] : 0.f;
      v *= ((nt & 3) == 2) ? (2.f * KLOG2E) : (-KLOG2E);
      wih_f[idx] = (_Float16)v;
      continue;
    }
    idx -= N_wih0;
    if (idx < N_wihr) {
      int e = idx & 7, lane = (idx >> 3) & 63, r = idx >> 9;
      int kc = r % 10; r /= 10; int nt = r % 40; int ld = r / 40;
      int jrow = (nt >> 2) * 16 + (lane & 15);
      int g = (nt & 3) * 150 + jrow;
      int k = 32 * kc + 16 * (e >> 2) + 4 * (lane >> 4) + (e & 3);
      float v = (jrow < 150 && k < 300) ? WihR[((size_t)ld * 600 + g) * 300 + k] : 0.f;
      v *= ((nt & 3) == 2) ? (2.f * KLOG2E) : (-KLOG2E);
      wih_f[N_wih0 + idx] = (_Float16)v;
      continue;
    }
    idx -= N_wihr;
    if (idx < N_wpr) {
      int e = idx & 7, lane = (idx >> 3) & 63, r = idx >> 9;
      int kc = r % 10; int nt = r / 10;
      int ko = 16 * nt + (lane & 15);
      int k = 32 * kc + 16 * (e >> 2) + 4 * (lane >> 4) + (e & 3);
      float v = 0.f;
      if (k < 300) {
        if (ko < 100) v = w1m[(size_t)ko * 600 + k];
        else if (ko < 200) v = w1m[(size_t)(ko - 100) * 600 + 300 + k];
      }
      wpr_f[idx] = (_Float16)v;
      continue;
    }
    idx -= N_wpr;
    if (idx < N_bs) {
      int ld = idx / 640, gp = idx - 640 * ld;
      int nt = gp >> 4, lrow = gp & 15;
      int jrow = (nt >> 2) * 16 + lrow;
      int g = (nt & 3) * 150 + jrow;
      float v = (jrow < 150) ? bih[ld * 600 + g] + bhh[ld * 600 + g] : 0.f;
      v *= ((nt & 3) == 2) ? (2.f * KLOG2E) : (-KLOG2E);
      bsum[idx] = v;
      continue;
    }
    idx -= N_bs;
    if (idx < 256) {
      b1cat[idx] = (idx < 100) ? b1v[idx] : ((idx < 200) ? b1v[idx - 100] : 0.f);
      continue;
    }
    idx -= 256;
    // embedding gather: idx over [1536][320]
    {
      int row = idx / 320, j = idx - 320 * row;
      int b = row & 15, t = row >> 4;
      float v = 0.f;
      if (j < 100) v = wemb[(size_t)widx[b * 96 + t] * 100 + j];
      else if (j < 150) v = temb[(size_t)pidx[b * 96 + t] * 50 + (j - 100)];
      xa[idx] = (_Float16)v;
      if (j >= 300) xb[idx] = (_Float16)0.f;
    }
  }
}

// ---------------- pre-GEMM: writes scan-fragment-ordered PRE chunks ----------------
template <int KC>
__global__ __launch_bounds__(512) void pregemm_kernel(
    const _Float16* __restrict__ x_h,
    const _Float16* __restrict__ wih_f,
    const float* __restrict__ bsum_l,
    float* __restrict__ pre)            // [2][96][640][16]
{
  const int t = blockIdx.x, dir = blockIdx.y;
  const int tid = threadIdx.x, wv = tid >> 6, lane = tid & 63;
  const int lrow = lane & 15, lgrp = lane >> 4;
  const _Float16* wf = wih_f + (size_t)dir * 40 * KC * 512;
  float4v acc[5];
#pragma unroll
  for (int tt = 0; tt < 5; ++tt) acc[tt] = (float4v){0.f, 0.f, 0.f, 0.f};
  const size_t arow = ((size_t)t * 16 + lrow) * 320;
#pragma unroll
  for (int kc = 0; kc < KC; ++kc) {
    int co = 32 * kc + 4 * lgrp;
    half8 ah = cat44h(*(const half4*)(x_h + arow + co),
                      *(const half4*)(x_h + arow + co + 16));
#pragma unroll
    for (int tt = 0; tt < 5; ++tt) {
      int nt = 5 * wv + tt;
      const size_t wo = ((size_t)(nt * KC + kc) * 64 + lane) * 8;
      half8 bw = *(const half8*)(wf + wo);
      acc[tt] = mfma16h(ah, bw, acc[tt]);
    }
  }
  float* po = pre + (size_t)(dir * 96 + t) * 10240;
  const float* bs = bsum_l + dir * 640;
#pragma unroll
  for (int tt = 0; tt < 5; ++tt) {
    int nt = 5 * wv + tt;
    float bv = bs[16 * nt + lrow];
    float4v v;
#pragma unroll
    for (int jj = 0; jj < 4; ++jj) v[jj] = acc[tt][jj] + bv;
    int tid_s = (nt >> 2) * 64 + lgrp * 16 + lrow;   // scan-thread owner
    *(float4v*)(po + (size_t)tid_s * 16 + (nt & 3) * 4) = v;
  }
}

// ---------------- sequential LSTM scan: 10 waves, gates thread-local ----------------
// Counted barrier (lgkmcnt only -- prefetch loads stay in flight across steps),
// pair-batched rcp gate math (24 trans/thread vs 32), one barrier/step.
__global__ __launch_bounds__(640, 1) void scan_kernel(
    const float* __restrict__ pre,                 // [2][96][640][16]
    const _Float16* __restrict__ whh_f,
    _Float16* __restrict__ xo,                     // [1536][320]
    int layer)
{
  const int dir = blockIdx.x;
  const int tid = threadIdx.x, wv = tid >> 6, lane = tid & 63;
  const int lrow = lane & 15, lgrp = lane >> 4;

  // h in MFMA A-fragment order, row stride 172 (conflict-free ds_read_b128)
  __shared__ __align__(16) _Float16 hb[2][16 * 172];

  for (int i = tid; i < 2 * 16 * 172; i += 640)
    (&hb[0][0])[i] = (_Float16)0.f;

  // Whh fragments resident: 4 gate-quad tiles x 5 kc per wave (40 VGPR)
  const _Float16* b_base = whh_f + (size_t)(layer * 2 + dir) * 40 * 5 * 512;
  half8 Bw[4][5];
#pragma unroll
  for (int tt = 0; tt < 4; ++tt)
#pragma unroll
    for (int kc = 0; kc < 5; ++kc) {
      size_t o = ((size_t)((4 * wv + tt) * 5 + kc) * 64 + lane) * 8;
      Bw[tt][kc] = *(const half8*)(b_base + o);
    }

  float cst[4] = {0.f, 0.f, 0.f, 0.f};
  const int j = 16 * wv + lrow;          // this thread's cell column
  const int kcj = j >> 5, wj = j & 31;   // h-fragment slot for (b, j)
  const int hoff = kcj * 32 + ((wj >> 2) & 3) * 8 + (wj >> 4) * 4 + (wj & 3);
  const bool jok = (j < 150);

  const int t0 = dir ? 95 : 0;
  const long pincv = dir ? -2560 : 2560;           // float4v per t step
  const long xinc = dir ? -(16 * 320) : (16 * 320);
  const float4v* pc = (const float4v*)pre + ((size_t)(dir * 96 + t0) * 640 + tid) * 4;
  _Float16* xop = xo + ((size_t)t0 * 16 + 4 * lgrp) * 320 + dir * 150 + j;

  float4v pfA[4], pfB[4];
#pragma unroll
  for (int i = 0; i < 4; ++i) pfA[i] = pc[i];
  pc += pincv;
#pragma unroll
  for (int i = 0; i < 4; ++i) pfB[i] = pc[i];
  pc += pincv;
  __syncthreads();

#define SCAN_STEP(PF, HIN, HOUT)                                          \
  {                                                                       \
    _Pragma("unroll")                                                     \
    for (int kc = 0; kc < 5; ++kc) {                                      \
      const int ao = lrow * 172 + kc * 32 + lgrp * 8;                     \
      half8 ah = *(const half8*)((HIN) + ao);                             \
      _Pragma("unroll")                                                   \
      for (int tt = 0; tt < 4; ++tt)                                      \
        PF[tt] = mfma16h(ah, Bw[tt][kc], PF[tt]);                         \
    }                                                                     \
    float zo_[4], Dq[4], Nq[4], cv[4];                                    \
    _Pragma("unroll")                                                     \
    for (int jj = 0; jj < 4; ++jj) {                                      \
      float zi = __builtin_amdgcn_exp2f(PF[0][jj]);                       \
      float zf = __builtin_amdgcn_exp2f(PF[1][jj]);                       \
      float zg = __builtin_amdgcn_exp2f(PF[2][jj]);                       \
      zo_[jj]  = __builtin_amdgcn_exp2f(PF[3][jj]);                       \
      float tq = (1.f + zi) * (zg + 1.f);                                 \
      float fq = 1.f + zf;                                                \
      Dq[jj] = tq * fq;                                                   \
      Nq[jj] = cst[jj] * tq + (zg - 1.f) * fq;                            \
    }                                                                     \
    {                                                                     \
      float rP0 = __builtin_amdgcn_rcpf(Dq[0] * Dq[1]);                   \
      float rP1 = __builtin_amdgcn_rcpf(Dq[2] * Dq[3]);                   \
      cv[0] = Nq[0] * rP0 * Dq[1];                                        \
      cv[1] = Nq[1] * rP0 * Dq[0];                                        \
      cv[2] = Nq[2] * rP1 * Dq[3];                                        \
      cv[3] = Nq[3] * rP1 * Dq[2];                                        \
    }                                                                     \
    float zc_[4], Eq[4];                                                  \
    _Pragma("unroll")                                                     \
    for (int jj = 0; jj < 4; ++jj) {                                      \
      cst[jj] = cv[jj];                                                   \
      zc_[jj] = __builtin_amdgcn_exp2f(2.f * KLOG2E * cv[jj]);            \
      Eq[jj] = (1.f + zo_[jj]) * (zc_[jj] + 1.f);                         \
    }                                                                     \
    {                                                                     \
      float rE0 = __builtin_amdgcn_rcpf(Eq[0] * Eq[1]);                   \
      float rE1 = __builtin_amdgcn_rcpf(Eq[2] * Eq[3]);                   \
      float hv0 = (zc_[0] - 1.f) * rE0 * Eq[1];                           \
      float hv1 = (zc_[1] - 1.f) * rE0 * Eq[0];                           \
      float hv2 = (zc_[2] - 1.f) * rE1 * Eq[3];                           \
      float hv3 = (zc_[3] - 1.f) * rE1 * Eq[2];                           \
      _Float16 h0 = (_Float16)hv0, h1 = (_Float16)hv1;                    \
      _Float16 h2 = (_Float16)hv2, h3 = (_Float16)hv3;                    \
      (HOUT)[(4 * lgrp + 0) * 172 + hoff] = h0;                           \
      (HOUT)[(4 * lgrp + 1) * 172 + hoff] = h1;                           \
      (HOUT)[(4 * lgrp + 2) * 172 + hoff] = h2;                          \
      (HOUT)[(4 * lgrp + 3) * 172 + hoff] = h3;                           \
      if (jok) {                                                          \
        xop[0 * 320] = h0; xop[1 * 320] = h1;                             \
        xop[2 * 320] = h2; xop[3 * 320] = h3;                             \
      }                                                                   \
    }                                                                     \
    _Pragma("unroll")                                                     \
    for (int i = 0; i < 4; ++i) PF[i] = pc[i];                            \
    pc += pincv;                                                          \
    xop += xinc;                                                          \
    asm volatile("s_waitcnt lgkmcnt(0)" ::: "memory");                    \
    __builtin_amdgcn_s_barrier();                                         \
  }

#pragma unroll 1
  for (int s2 = 0; s2 < 48; ++s2) {
    SCAN_STEP(pfA, hb[0], hb[1]);
    SCAN_STEP(pfB, hb[1], hb[0]);
  }
#undef SCAN_STEP
}

// ---------------- projection (poly fused in via LDS stage) ----------------
// AD[row][0:100]=A+b1, [100:200]=D
__global__ __launch_bounds__(512) void proj_kernel(
    const _Float16* __restrict__ xi,      // [1536][320] layer-3 output
    const _Float16* __restrict__ wpr_f,
    const float* __restrict__ b1cat,
    const float* __restrict__ w1, const float* __restrict__ w2,
    const float* __restrict__ w3, const float* __restrict__ w4,
    float* __restrict__ AD)   // [1536][256]
{
  const int t = blockIdx.x;
  const int tid = threadIdx.x, wv = tid >> 6, lane = tid & 63;
  const int lrow = lane & 15, lgrp = lane >> 4;
  __shared__ __align__(16) _Float16 ph[16 * 328];  // stride 328: 2-way conflicts only
  __shared__ __align__(16) _Float16 pl[16 * 328];
  {
    float c1 = w1[0], c2 = w2[0], c3 = w3[0], c4 = w4[0];
    for (int e = tid; e < 16 * 320; e += 512) {
      int row = e / 320, col = e - 320 * row;
      float x = (float)xi[(size_t)t * 5120 + e];
      float p = x * (c1 + x * (c2 + x * (c3 + x * c4)));
      _Float16 h, l; split_f16(p, h, l);
      ph[row * 328 + col] = h; pl[row * 328 + col] = l;
    }
  }
  __syncthreads();
  float4v acc[2] = {{0.f, 0.f, 0.f, 0.f}, {0.f, 0.f, 0.f, 0.f}};
#pragma unroll
  for (int kc = 0; kc < 10; ++kc) {
    int co = lrow * 328 + 32 * kc + 4 * lgrp;
    half8 ah = cat44h(*(const half4*)(ph + co), *(const half4*)(ph + co + 16));
    half8 al = cat44h(*(const half4*)(pl + co), *(const half4*)(pl + co + 16));
#pragma unroll
    for (int tt = 0; tt < 2; ++tt) {
      int nt = 2 * wv + tt;
      size_t wo = ((size_t)(nt * 10 + kc) * 64 + lane) * 8;
      half8 bw = *(const half8*)(wpr_f + wo);
      acc[tt] = mfma16h(ah, bw, acc[tt]);
      acc[tt] = mfma16h(al, bw, acc[tt]);
    }
  }
#pragma unroll
  for (int tt = 0; tt < 2; ++tt) {
    int ko = 16 * (2 * wv + tt) + lrow;
    float bv = b1cat[ko];
#pragma unroll
    for (int jj = 0; jj < 4; ++jj)
      AD[((size_t)t * 16 + 4 * lgrp + jj) * 256 + ko] = acc[tt][jj] + bv;
  }
}

// ---------------- combine: out[lh][b][ld] = b2 + sum_k w2[k]*tanh(A+D) ----------------
__global__ __launch_bounds__(768) void combine_kernel(
    const float* __restrict__ AD, const float* __restrict__ w2v,
    const float* __restrict__ b2v, float* __restrict__ out)
{
  const int bb = blockIdx.x & 15, lt = blockIdx.x >> 4;
  const int tid = threadIdx.x;
  __shared__ float Dl[100 * 97];  // [k][ld], stride 97
  __shared__ float Al[100 * 9];   // [k][lh], stride 9
  __shared__ float w2s[100];
  for (int i = tid; i < 96 * 32; i += 768) {
    int ld = i >> 5, f4 = i & 31;
    if (f4 < 25) {
      float4v v = *(const float4v*)(AD + ((size_t)ld * 16 + bb) * 256 + 100 + 4 * f4);
      int k0 = 4 * f4;
      Dl[(k0 + 0) * 97 + ld] = v[0];
      Dl[(k0 + 1) * 97 + ld] = v[1];
      Dl[(k0 + 2) * 97 + ld] = v[2];
      Dl[(k0 + 3) * 97 + ld] = v[3];
    }
  }
  for (int i = tid; i < 8 * 32; i += 768) {
    int lh = i >> 5, f4 = i & 31;
    if (f4 < 25) {
      int lseq = lt * 8 + lh;
      float4v v = *(const float4v*)(AD + ((size_t)lseq * 16 + bb) * 256 + 4 * f4);
      int k0 = 4 * f4;
      Al[(k0 + 0) * 9 + lh] = v[0];
      Al[(k0 + 1) * 9 + lh] = v[1];
      Al[(k0 + 2) * 9 + lh] = v[2];
      Al[(k0 + 3) * 9 + lh] = v[3];
    }
  }
  if (tid < 100) w2s[tid] = w2v[tid];
  __syncthreads();
  int lh = tid / 96, ld = tid - 96 * lh;
  float s = 0.f;
#pragma unroll 4
  for (int k = 0; k < 100; ++k) {
    float x = Al[k * 9 + lh] + Dl[k * 97 + ld];
    s += w2s[k] * fast_tanh(x);
  }
  out[((size_t)(lt * 8 + lh) * 16 + bb) * 96 + ld] = s + b2v[0];
}

// ---------------- host ----------------
extern "C" void kernel_launch(void* const* d_in, const int* in_sizes, int n_in,
                              void* d_out, int out_size, void* d_ws, size_t ws_size,
                              hipStream_t stream)
{
  const int*   widx = (const int*)d_in[0];
  const int*   pidx = (const int*)d_in[1];
  const float* wemb = (const float*)d_in[3];
  const float* temb = (const float*)d_in[4];
  const float* Wih0 = (const float*)d_in[5];
  const float* WihR = (const float*)d_in[6];
  const float* Whh  = (const float*)d_in[7];
  const float* bih  = (const float*)d_in[8];
  const float* bhh  = (const float*)d_in[9];
  const float* w1   = (const float*)d_in[10];
  const float* w2   = (const float*)d_in[11];
  const float* w3   = (const float*)d_in[12];
  const float* w4   = (const float*)d_in[13];
  const float* w1m  = (const float*)d_in[14];
  const float* b1v  = (const float*)d_in[15];
  const float* w2m  = (const float*)d_in[16];
  const float* b2v  = (const float*)d_in[17];
  float* out = (float*)d_out;

  char* ws = (char*)d_ws;
  size_t off = 0;
  auto alloc = [&](size_t bytes) -> char* {
    char* p = ws + off;
    off = (off + bytes + 255) & ~(size_t)255;
    return p;
  };
  _Float16* WHH_F = (_Float16*)alloc(819200ull * 2);
  _Float16* WIH_F = (_Float16*)alloc(1433600ull * 2);
  _Float16* WPR_F = (_Float16*)alloc(81920ull * 2);
  float* BSUM = (float*)alloc(5120ull * 4);
  float* B1C  = (float*)alloc(256ull * 4);
  _Float16* XA = (_Float16*)alloc(491520ull * 2);
  _Float16* XB = (_Float16*)alloc(491520ull * 2);
  float* PRE = (float*)alloc(1966080ull * 4);
  float* AD  = (float*)alloc(1536ull * 256 * 4);

  prep_kernel<<<512, 256, 0, stream>>>(Wih0, WihR, Whh, bih, bhh, w1m, b1v,
      widx, pidx, wemb, temb,
      WHH_F, WIH_F, WPR_F, BSUM, B1C, XA, XB);

  for (int layer = 0; layer < 4; ++layer) {
    const _Float16* xin = (layer & 1) ? XB : XA;
    _Float16* xout = (layer & 1) ? XA : XB;
    const float* bsl = BSUM + layer * 2 * 640;
    if (layer == 0) {
      pregemm_kernel<5><<<dim3(96, 2), 512, 0, stream>>>(xin, WIH_F, bsl, PRE);
    } else {
      size_t wo = 204800ull + (size_t)(layer - 1) * 409600ull;
      pregemm_kernel<10><<<dim3(96, 2), 512, 0, stream>>>(xin, WIH_F + wo, bsl, PRE);
    }
    scan_kernel<<<2, 640, 0, stream>>>(PRE, WHH_F, xout, layer);
  }
  // layer-3 output sits in XA; proj (poly fused) -> AD; combine -> out
  proj_kernel<<<96, 512, 0, stream>>>(XA, WPR_F, B1C, w1, w2, w3, w4, AD);
  combine_kernel<<<192, 768, 0, stream>>>(AD, w2m, b2v, out);
}

// Round 9
// 510.168 us; speedup vs baseline: 5.9737x; 1.0374x over previous
//
#include <hip/hip_runtime.h>

// ---------------- types / helpers ----------------
typedef __attribute__((ext_vector_type(8))) _Float16 half8;
typedef __attribute__((ext_vector_type(4))) _Float16 half4;
typedef __attribute__((ext_vector_type(4))) float float4v;

__device__ __forceinline__ float4v mfma16h(half8 a, half8 b, float4v c) {
  return __builtin_amdgcn_mfma_f32_16x16x32_f16(a, b, c, 0, 0, 0);
}

__device__ __forceinline__ half8 cat44h(half4 a, half4 b) {
  half8 r;
  r[0]=a[0]; r[1]=a[1]; r[2]=a[2]; r[3]=a[3];
  r[4]=b[0]; r[5]=b[1]; r[6]=b[2]; r[7]=b[3];
  return r;
}

__device__ __forceinline__ void split_f16(float x, _Float16& hi, _Float16& lo) {
  hi = (_Float16)x;                 // RNE
  lo = (_Float16)(x - (float)hi);
}

#define KLOG2E 1.442695041f
__device__ __forceinline__ float fast_tanh(float x) {
  float z = __builtin_amdgcn_exp2f(2.f * KLOG2E * x);
  return 1.f - 2.f * __builtin_amdgcn_rcpf(1.f + z);
}

// sizes: B=16 L=96 H=150 4H=600(pad 640) EMB=150(pad 160) 2H=300(pad 320)
// fragment slot formula (same for A and B operands; permutation cancels):
//   k(lane,e) = 32*kc + 16*(e>>2) + 4*(lane>>4) + (e&3)
// GATE-QUAD permutation: tile nt = jg*4 + gate, source row g = gate*150 + jg*16 + lrow.
// GATE-SCALE folding: rows pre-scaled by (-log2e) for i,f,o and (+2log2e) for g.
// PRE layout: [dir][t][tid(640)][16].
// X layout (PADDED): row=t*16+b, 320 cols: dir0 h at [0,160), dir1 at [160,320);
//   cols 150..159 and 310..319 are pad (h==0 there by construction); weight K
//   columns for those slots are zeroed in prep (k>=160 reads source k-10).

// ---------------- prep: weight fragments + embedding gather (fused) ----------
__global__ void prep_kernel(
    const float* __restrict__ Wih0,   // [2][600][150]
    const float* __restrict__ WihR,   // [3][2][600][300]
    const float* __restrict__ Whh,    // [4][2][600][150]
    const float* __restrict__ bih,    // [4][2][600]
    const float* __restrict__ bhh,    // [4][2][600]
    const float* __restrict__ w1m,    // [100][600]
    const float* __restrict__ b1v,    // [100]
    const int* __restrict__ widx, const int* __restrict__ pidx,
    const float* __restrict__ wemb, const float* __restrict__ temb,
    _Float16* __restrict__ whh_f,
    _Float16* __restrict__ wih_f,
    _Float16* __restrict__ wpr_f,
    float* __restrict__ bsum, float* __restrict__ b1cat,
    _Float16* __restrict__ xa)
{
  const int N_whh  = 8 * 40 * 5 * 512;   // 819200
  const int N_wih0 = 2 * 40 * 5 * 512;   // 204800
  const int N_wihr = 6 * 40 * 10 * 512;  // 1228800
  const int N_wpr  = 16 * 10 * 512;      // 81920
  const int N_bs   = 8 * 640;            // 5120
  const int N_emb  = 1536 * 320;         // 491520
  const int total  = N_whh + N_wih0 + N_wihr + N_wpr + N_bs + 256 + N_emb;
  for (int i = blockIdx.x * blockDim.x + threadIdx.x; i < total;
       i += gridDim.x * blockDim.x) {
    int idx = i;
    if (idx < N_whh) {
      int e = idx & 7, lane = (idx >> 3) & 63, r = idx >> 9;
      int kc = r % 5; r /= 5; int nt = r % 40; int ld = r / 40;
      int jrow = (nt >> 2) * 16 + (lane & 15);
      int g = (nt & 3) * 150 + jrow;
      int k = 32 * kc + 16 * (e >> 2) + 4 * (lane >> 4) + (e & 3);
      float v = (jrow < 150 && k < 150) ? Whh[((size_t)ld * 600 + g) * 150 + k] : 0.f;
      v *= ((nt & 3) == 2) ? (2.f * KLOG2E) : (-KLOG2E);
      whh_f[idx] = (_Float16)v;
      continue;
    }
    idx -= N_whh;
    if (idx < N_wih0) {
      int e = idx & 7, lane = (idx >> 3) & 63, r = idx >> 9;
      int kc = r % 5; r /= 5; int nt = r % 40; int dir = r / 40;
      int jrow = (nt >> 2) * 16 + (lane & 15);
      int g = (nt & 3) * 150 + jrow;
      int k = 32 * kc + 16 * (e >> 2) + 4 * (lane >> 4) + (e & 3);
      float v = (jrow < 150 && k < 150) ? Wih0[((size_t)dir * 600 + g) * 150 + k] : 0.f;
      v *= ((nt & 3) == 2) ? (2.f * KLOG2E) : (-KLOG2E);
      wih_f[idx] = (_Float16)v;
      continue;
    }
    idx -= N_wih0;
    if (idx < N_wihr) {
      int e = idx & 7, lane = (idx >> 3) & 63, r = idx >> 9;
      int kc = r % 10; r /= 10; int nt = r % 40; int ld = r / 40;
      int jrow = (nt >> 2) * 16 + (lane & 15);
      int g = (nt & 3) * 150 + jrow;
      int k = 32 * kc + 16 * (e >> 2) + 4 * (lane >> 4) + (e & 3);
      // padded-X remap: x cols [0,150)=dir0 h, [160,310)=dir1 h, rest pad(zero)
      int ks = (k < 150) ? k : ((k >= 160 && k < 310) ? (k - 10) : -1);
      float v = (jrow < 150 && ks >= 0) ? WihR[((size_t)ld * 600 + g) * 300 + ks] : 0.f;
      v *= ((nt & 3) == 2) ? (2.f * KLOG2E) : (-KLOG2E);
      wih_f[N_wih0 + idx] = (_Float16)v;
      continue;
    }
    idx -= N_wihr;
    if (idx < N_wpr) {
      int e = idx & 7, lane = (idx >> 3) & 63, r = idx >> 9;
      int kc = r % 10; int nt = r / 10;
      int ko = 16 * nt + (lane & 15);
      int k = 32 * kc + 16 * (e >> 2) + 4 * (lane >> 4) + (e & 3);
      int ks = (k < 150) ? k : ((k >= 160 && k < 310) ? (k - 10) : -1);
      float v = 0.f;
      if (ks >= 0) {
        if (ko < 100) v = w1m[(size_t)ko * 600 + ks];
        else if (ko < 200) v = w1m[(size_t)(ko - 100) * 600 + 300 + ks];
      }
      wpr_f[idx] = (_Float16)v;
      continue;
    }
    idx -= N_wpr;
    if (idx < N_bs) {
      int ld = idx / 640, gp = idx - 640 * ld;
      int nt = gp >> 4, lrow = gp & 15;
      int jrow = (nt >> 2) * 16 + lrow;
      int g = (nt & 3) * 150 + jrow;
      float v = (jrow < 150) ? bih[ld * 600 + g] + bhh[ld * 600 + g] : 0.f;
      v *= ((nt & 3) == 2) ? (2.f * KLOG2E) : (-KLOG2E);
      bsum[idx] = v;
      continue;
    }
    idx -= N_bs;
    if (idx < 256) {
      b1cat[idx] = (idx < 100) ? b1v[idx] : ((idx < 200) ? b1v[idx - 100] : 0.f);
      continue;
    }
    idx -= 256;
    // embedding gather: idx over [1536][320] (cols >=150 zero)
    {
      int row = idx / 320, j = idx - 320 * row;
      int b = row & 15, t = row >> 4;
      float v = 0.f;
      if (j < 100) v = wemb[(size_t)widx[b * 96 + t] * 100 + j];
      else if (j < 150) v = temb[(size_t)pidx[b * 96 + t] * 50 + (j - 100)];
      xa[idx] = (_Float16)v;
    }
  }
}

// ---------------- pre-GEMM: writes scan-fragment-ordered PRE chunks ----------------
template <int KC>
__global__ __launch_bounds__(512) void pregemm_kernel(
    const _Float16* __restrict__ x_h,
    const _Float16* __restrict__ wih_f,
    const float* __restrict__ bsum_l,
    float* __restrict__ pre)            // [2][96][640][16]
{
  const int t = blockIdx.x, dir = blockIdx.y;
  const int tid = threadIdx.x, wv = tid >> 6, lane = tid & 63;
  const int lrow = lane & 15, lgrp = lane >> 4;
  const _Float16* wf = wih_f + (size_t)dir * 40 * KC * 512;
  float4v acc[5];
#pragma unroll
  for (int tt = 0; tt < 5; ++tt) acc[tt] = (float4v){0.f, 0.f, 0.f, 0.f};
  const size_t arow = ((size_t)t * 16 + lrow) * 320;
#pragma unroll
  for (int kc = 0; kc < KC; ++kc) {
    int co = 32 * kc + 4 * lgrp;
    half8 ah = cat44h(*(const half4*)(x_h + arow + co),
                      *(const half4*)(x_h + arow + co + 16));
#pragma unroll
    for (int tt = 0; tt < 5; ++tt) {
      int nt = 5 * wv + tt;
      const size_t wo = ((size_t)(nt * KC + kc) * 64 + lane) * 8;
      half8 bw = *(const half8*)(wf + wo);
      acc[tt] = mfma16h(ah, bw, acc[tt]);
    }
  }
  float* po = pre + (size_t)(dir * 96 + t) * 10240;
  const float* bs = bsum_l + dir * 640;
#pragma unroll
  for (int tt = 0; tt < 5; ++tt) {
    int nt = 5 * wv + tt;
    float bv = bs[16 * nt + lrow];
    float4v v;
#pragma unroll
    for (int jj = 0; jj < 4; ++jj) v[jj] = acc[tt][jj] + bv;
    int tid_s = (nt >> 2) * 64 + lgrp * 16 + lrow;   // scan-thread owner
    *(float4v*)(po + (size_t)tid_s * 16 + (nt & 3) * 4) = v;
  }
}

// ---------------- sequential LSTM scan: 10 waves, gates thread-local ----------------
// Counted barrier; pair-batched rcp gate math; padded xo (no branch); store-source
// registers double-buffered across step parity (keep-alive) so h-stores retire
// without forcing a vmcnt wait before the next step's h rewrite.
__global__ __launch_bounds__(640, 1) void scan_kernel(
    const float* __restrict__ pre,                 // [2][96][640][16]
    const _Float16* __restrict__ whh_f,
    _Float16* __restrict__ xo,                     // [1536][320] padded layout
    int layer)
{
  const int dir = blockIdx.x;
  const int tid = threadIdx.x, wv = tid >> 6, lane = tid & 63;
  const int lrow = lane & 15, lgrp = lane >> 4;

  // h in MFMA A-fragment order, row stride 172 (conflict-free ds_read_b128)
  __shared__ __align__(16) _Float16 hb[2][16 * 172];

  for (int i = tid; i < 2 * 16 * 172; i += 640)
    (&hb[0][0])[i] = (_Float16)0.f;

  // Whh fragments resident: 4 gate-quad tiles x 5 kc per wave (40 VGPR)
  const _Float16* b_base = whh_f + (size_t)(layer * 2 + dir) * 40 * 5 * 512;
  half8 Bw[4][5];
#pragma unroll
  for (int tt = 0; tt < 4; ++tt)
#pragma unroll
    for (int kc = 0; kc < 5; ++kc) {
      size_t o = ((size_t)((4 * wv + tt) * 5 + kc) * 64 + lane) * 8;
      Bw[tt][kc] = *(const half8*)(b_base + o);
    }

  float cst[4] = {0.f, 0.f, 0.f, 0.f};
  const int j = 16 * wv + lrow;          // this thread's cell column
  const int kcj = j >> 5, wj = j & 31;   // h-fragment slot for (b, j)
  const int hoff = kcj * 32 + ((wj >> 2) & 3) * 8 + (wj >> 4) * 4 + (wj & 3);

  const int t0 = dir ? 95 : 0;
  const long pincv = dir ? -2560 : 2560;           // float4v per t step
  const long xinc = dir ? -(16 * 320) : (16 * 320);
  const float4v* pc = (const float4v*)pre + ((size_t)(dir * 96 + t0) * 640 + tid) * 4;
  _Float16* xop = xo + ((size_t)t0 * 16 + 4 * lgrp) * 320 + dir * 160 + j;

  float4v pfA[4], pfB[4];
#pragma unroll
  for (int i = 0; i < 4; ++i) pfA[i] = pc[i];
  pc += pincv;
#pragma unroll
  for (int i = 0; i < 4; ++i) pfB[i] = pc[i];
  pc += pincv;

  // per-parity store-source registers (keep-alive pins liveness ~2 steps)
  _Float16 hsA0 = 0, hsA1 = 0, hsA2 = 0, hsA3 = 0;
  _Float16 hsB0 = 0, hsB1 = 0, hsB2 = 0, hsB3 = 0;
  __syncthreads();

#define SCAN_STEP(PF, H0, H1, H2, H3, O0, O1, O2, O3, HIN, HOUT)          \
  {                                                                       \
    asm volatile("" :: "v"(O0), "v"(O1), "v"(O2), "v"(O3));               \
    _Pragma("unroll")                                                     \
    for (int kc = 0; kc < 5; ++kc) {                                      \
      const int ao = lrow * 172 + kc * 32 + lgrp * 8;                     \
      half8 ah = *(const half8*)((HIN) + ao);                             \
      _Pragma("unroll")                                                   \
      for (int tt = 0; tt < 4; ++tt)                                      \
        PF[tt] = mfma16h(ah, Bw[tt][kc], PF[tt]);                         \
    }                                                                     \
    float zo_[4], Dq[4], Nq[4], cv[4];                                    \
    _Pragma("unroll")                                                     \
    for (int jj = 0; jj < 4; ++jj) {                                      \
      float zi = __builtin_amdgcn_exp2f(PF[0][jj]);                       \
      float zf = __builtin_amdgcn_exp2f(PF[1][jj]);                       \
      float zg = __builtin_amdgcn_exp2f(PF[2][jj]);                       \
      zo_[jj]  = __builtin_amdgcn_exp2f(PF[3][jj]);                       \
      float tq = (1.f + zi) * (zg + 1.f);                                 \
      float fq = 1.f + zf;                                                \
      Dq[jj] = tq * fq;                                                   \
      Nq[jj] = cst[jj] * tq + (zg - 1.f) * fq;                            \
    }                                                                     \
    {                                                                     \
      float rP0 = __builtin_amdgcn_rcpf(Dq[0] * Dq[1]);                   \
      float rP1 = __builtin_amdgcn_rcpf(Dq[2] * Dq[3]);                   \
      cv[0] = Nq[0] * rP0 * Dq[1];                                        \
      cv[1] = Nq[1] * rP0 * Dq[0];                                        \
      cv[2] = Nq[2] * rP1 * Dq[3];                                        \
      cv[3] = Nq[3] * rP1 * Dq[2];                                        \
    }                                                                     \
    float zc_[4], Eq[4];                                                  \
    _Pragma("unroll")                                                     \
    for (int jj = 0; jj < 4; ++jj) {                                      \
      cst[jj] = cv[jj];                                                   \
      zc_[jj] = __builtin_amdgcn_exp2f(2.f * KLOG2E * cv[jj]);            \
      Eq[jj] = (1.f + zo_[jj]) * (zc_[jj] + 1.f);                         \
    }                                                                     \
    {                                                                     \
      float rE0 = __builtin_amdgcn_rcpf(Eq[0] * Eq[1]);                   \
      float rE1 = __builtin_amdgcn_rcpf(Eq[2] * Eq[3]);                   \
      H0 = (_Float16)((zc_[0] - 1.f) * rE0 * Eq[1]);                      \
      H1 = (_Float16)((zc_[1] - 1.f) * rE0 * Eq[0]);                      \
      H2 = (_Float16)((zc_[2] - 1.f) * rE1 * Eq[3]);                      \
      H3 = (_Float16)((zc_[3] - 1.f) * rE1 * Eq[2]);                      \
      (HOUT)[(4 * lgrp + 0) * 172 + hoff] = H0;                           \
      (HOUT)[(4 * lgrp + 1) * 172 + hoff] = H1;                           \
      (HOUT)[(4 * lgrp + 2) * 172 + hoff] = H2;                           \
      (HOUT)[(4 * lgrp + 3) * 172 + hoff] = H3;                           \
      xop[0 * 320] = H0; xop[1 * 320] = H1;                               \
      xop[2 * 320] = H2; xop[3 * 320] = H3;                               \
    }                                                                     \
    _Pragma("unroll")                                                     \
    for (int i = 0; i < 4; ++i) PF[i] = pc[i];                            \
    pc += pincv;                                                          \
    xop += xinc;                                                          \
    asm volatile("s_waitcnt lgkmcnt(0)" ::: "memory");                    \
    __builtin_amdgcn_s_barrier();                                         \
  }

#pragma unroll 1
  for (int s2 = 0; s2 < 48; ++s2) {
    SCAN_STEP(pfA, hsA0, hsA1, hsA2, hsA3, hsB0, hsB1, hsB2, hsB3, hb[0], hb[1]);
    SCAN_STEP(pfB, hsB0, hsB1, hsB2, hsB3, hsA0, hsA1, hsA2, hsA3, hb[1], hb[0]);
  }
#undef SCAN_STEP
}

// ---------------- projection (poly fused in via LDS stage) ----------------
// AD[row][0:100]=A+b1, [100:200]=D
__global__ __launch_bounds__(512) void proj_kernel(
    const _Float16* __restrict__ xi,      // [1536][320] layer-3 output (padded)
    const _Float16* __restrict__ wpr_f,
    const float* __restrict__ b1cat,
    const float* __restrict__ w1, const float* __restrict__ w2,
    const float* __restrict__ w3, const float* __restrict__ w4,
    float* __restrict__ AD)   // [1536][256]
{
  const int t = blockIdx.x;
  const int tid = threadIdx.x, wv = tid >> 6, lane = tid & 63;
  const int lrow = lane & 15, lgrp = lane >> 4;
  __shared__ __align__(16) _Float16 ph[16 * 328];  // stride 328: 2-way conflicts only
  __shared__ __align__(16) _Float16 pl[16 * 328];
  {
    float c1 = w1[0], c2 = w2[0], c3 = w3[0], c4 = w4[0];
    for (int e = tid; e < 16 * 320; e += 512) {
      int row = e / 320, col = e - 320 * row;
      float x = (float)xi[(size_t)t * 5120 + e];
      float p = x * (c1 + x * (c2 + x * (c3 + x * c4)));
      _Float16 h, l; split_f16(p, h, l);
      ph[row * 328 + col] = h; pl[row * 328 + col] = l;
    }
  }
  __syncthreads();
  float4v acc[2] = {{0.f, 0.f, 0.f, 0.f}, {0.f, 0.f, 0.f, 0.f}};
#pragma unroll
  for (int kc = 0; kc < 10; ++kc) {
    int co = lrow * 328 + 32 * kc + 4 * lgrp;
    half8 ah = cat44h(*(const half4*)(ph + co), *(const half4*)(ph + co + 16));
    half8 al = cat44h(*(const half4*)(pl + co), *(const half4*)(pl + co + 16));
#pragma unroll
    for (int tt = 0; tt < 2; ++tt) {
      int nt = 2 * wv + tt;
      size_t wo = ((size_t)(nt * 10 + kc) * 64 + lane) * 8;
      half8 bw = *(const half8*)(wpr_f + wo);
      acc[tt] = mfma16h(ah, bw, acc[tt]);
      acc[tt] = mfma16h(al, bw, acc[tt]);
    }
  }
#pragma unroll
  for (int tt = 0; tt < 2; ++tt) {
    int ko = 16 * (2 * wv + tt) + lrow;
    float bv = b1cat[ko];
#pragma unroll
    for (int jj = 0; jj < 4; ++jj)
      AD[((size_t)t * 16 + 4 * lgrp + jj) * 256 + ko] = acc[tt][jj] + bv;
  }
}

// ---------------- combine: out[lh][b][ld] = b2 + sum_k w2[k]*tanh(A+D) ----------------
__global__ __launch_bounds__(768) void combine_kernel(
    const float* __restrict__ AD, const float* __restrict__ w2v,
    const float* __restrict__ b2v, float* __restrict__ out)
{
  const int bb = blockIdx.x & 15, lt = blockIdx.x >> 4;
  const int tid = threadIdx.x;
  __shared__ float Dl[100 * 97];  // [k][ld], stride 97
  __shared__ float Al[100 * 9];   // [k][lh], stride 9
  __shared__ float w2s[100];
  for (int i = tid; i < 96 * 32; i += 768) {
    int ld = i >> 5, f4 = i & 31;
    if (f4 < 25) {
      float4v v = *(const float4v*)(AD + ((size_t)ld * 16 + bb) * 256 + 100 + 4 * f4);
      int k0 = 4 * f4;
      Dl[(k0 + 0) * 97 + ld] = v[0];
      Dl[(k0 + 1) * 97 + ld] = v[1];
      Dl[(k0 + 2) * 97 + ld] = v[2];
      Dl[(k0 + 3) * 97 + ld] = v[3];
    }
  }
  for (int i = tid; i < 8 * 32; i += 768) {
    int lh = i >> 5, f4 = i & 31;
    if (f4 < 25) {
      int lseq = lt * 8 + lh;
      float4v v = *(const float4v*)(AD + ((size_t)lseq * 16 + bb) * 256 + 4 * f4);
      int k0 = 4 * f4;
      Al[(k0 + 0) * 9 + lh] = v[0];
      Al[(k0 + 1) * 9 + lh] = v[1];
      Al[(k0 + 2) * 9 + lh] = v[2];
      Al[(k0 + 3) * 9 + lh] = v[3];
    }
  }
  if (tid < 100) w2s[tid] = w2v[tid];
  __syncthreads();
  int lh = tid / 96, ld = tid - 96 * lh;
  float s = 0.f;
#pragma unroll 4
  for (int k = 0; k < 100; ++k) {
    float x = Al[k * 9 + lh] + Dl[k * 97 + ld];
    s += w2s[k] * fast_tanh(x);
  }
  out[((size_t)(lt * 8 + lh) * 16 + bb) * 96 + ld] = s + b2v[0];
}

// ---------------- host ----------------
extern "C" void kernel_launch(void* const* d_in, const int* in_sizes, int n_in,
                              void* d_out, int out_size, void* d_ws, size_t ws_size,
                              hipStream_t stream)
{
  const int*   widx = (const int*)d_in[0];
  const int*   pidx = (const int*)d_in[1];
  const float* wemb = (const float*)d_in[3];
  const float* temb = (const float*)d_in[4];
  const float* Wih0 = (const float*)d_in[5];
  const float* WihR = (const float*)d_in[6];
  const float* Whh  = (const float*)d_in[7];
  const float* bih  = (const float*)d_in[8];
  const float* bhh  = (const float*)d_in[9];
  const float* w1   = (const float*)d_in[10];
  const float* w2   = (const float*)d_in[11];
  const float* w3   = (const float*)d_in[12];
  const float* w4   = (const float*)d_in[13];
  const float* w1m  = (const float*)d_in[14];
  const float* b1v  = (const float*)d_in[15];
  const float* w2m  = (const float*)d_in[16];
  const float* b2v  = (const float*)d_in[17];
  float* out = (float*)d_out;

  char* ws = (char*)d_ws;
  size_t off = 0;
  auto alloc = [&](size_t bytes) -> char* {
    char* p = ws + off;
    off = (off + bytes + 255) & ~(size_t)255;
    return p;
  };
  _Float16* WHH_F = (_Float16*)alloc(819200ull * 2);
  _Float16* WIH_F = (_Float16*)alloc(1433600ull * 2);
  _Float16* WPR_F = (_Float16*)alloc(81920ull * 2);
  float* BSUM = (float*)alloc(5120ull * 4);
  float* B1C  = (float*)alloc(256ull * 4);
  _Float16* XA = (_Float16*)alloc(491520ull * 2);
  _Float16* XB = (_Float16*)alloc(491520ull * 2);
  float* PRE = (float*)alloc(1966080ull * 4);
  float* AD  = (float*)alloc(1536ull * 256 * 4);

  prep_kernel<<<512, 256, 0, stream>>>(Wih0, WihR, Whh, bih, bhh, w1m, b1v,
      widx, pidx, wemb, temb,
      WHH_F, WIH_F, WPR_F, BSUM, B1C, XA);

  for (int layer = 0; layer < 4; ++layer) {
    const _Float16* xin = (layer & 1) ? XB : XA;
    _Float16* xout = (layer & 1) ? XA : XB;
    const float* bsl = BSUM + layer * 2 * 640;
    if (layer == 0) {
      pregemm_kernel<5><<<dim3(96, 2), 512, 0, stream>>>(xin, WIH_F, bsl, PRE);
    } else {
      size_t wo = 204800ull + (size_t)(layer - 1) * 409600ull;
      pregemm_kernel<10><<<dim3(96, 2), 512, 0, stream>>>(xin, WIH_F + wo, bsl, PRE);
    }
    scan_kernel<<<2, 640, 0, stream>>>(PRE, WHH_F, xout, layer);
  }
  // layer-3 output sits in XA; proj (poly fused) -> AD; combine -> out
  proj_kernel<<<96, 512, 0, stream>>>(XA, WPR_F, B1C, w1, w2, w3, w4, AD);
  combine_kernel<<<192, 768, 0, stream>>>(AD, w2m, b2v, out);
}

// Round 10
// 490.422 us; speedup vs baseline: 6.2142x; 1.0403x over previous
//
#include <hip/hip_runtime.h>

// ---------------- types / helpers ----------------
typedef __attribute__((ext_vector_type(8))) _Float16 half8;
typedef __attribute__((ext_vector_type(4))) _Float16 half4;
typedef __attribute__((ext_vector_type(4))) float float4v;
typedef __attribute__((ext_vector_type(2))) float float2v;

__device__ __forceinline__ float4v mfma16h(half8 a, half8 b, float4v c) {
  return __builtin_amdgcn_mfma_f32_16x16x32_f16(a, b, c, 0, 0, 0);
}

__device__ __forceinline__ half8 cat44h(half4 a, half4 b) {
  half8 r;
  r[0]=a[0]; r[1]=a[1]; r[2]=a[2]; r[3]=a[3];
  r[4]=b[0]; r[5]=b[1]; r[6]=b[2]; r[7]=b[3];
  return r;
}

__device__ __forceinline__ void split_f16(float x, _Float16& hi, _Float16& lo) {
  hi = (_Float16)x;                 // RNE
  lo = (_Float16)(x - (float)hi);
}

#define KLOG2E 1.442695041f
__device__ __forceinline__ float fast_tanh(float x) {
  float z = __builtin_amdgcn_exp2f(2.f * KLOG2E * x);
  return 1.f - 2.f * __builtin_amdgcn_rcpf(1.f + z);
}

// sizes: B=16 L=96 H=150 4H=600(pad 640) EMB=150(pad 160) 2H=300(pad 320)
// fragment slot formula (same for A and B operands; permutation cancels):
//   k(lane,e) = 32*kc + 16*(e>>2) + 4*(lane>>4) + (e&3)
// GATE-QUAD permutation: tile nt = jg*4 + gate, source row g = gate*150 + jg*16 + lrow.
// GATE-SCALE folding: rows pre-scaled by (-log2e) for i,f,o and (+2log2e) for g.
// PRE layout: [dir][t][tid(640)][16].
// X layout (PADDED): row=t*16+b, 320 cols: dir0 h at [0,160), dir1 at [160,320);
//   cols 150..159 and 310..319 are pad (zero); weight K columns remapped in prep.

// ---------------- prep: weight fragments + embedding gather (fused) ----------
__global__ void prep_kernel(
    const float* __restrict__ Wih0,   // [2][600][150]
    const float* __restrict__ WihR,   // [3][2][600][300]
    const float* __restrict__ Whh,    // [4][2][600][150]
    const float* __restrict__ bih,    // [4][2][600]
    const float* __restrict__ bhh,    // [4][2][600]
    const float* __restrict__ w1m,    // [100][600]
    const float* __restrict__ b1v,    // [100]
    const int* __restrict__ widx, const int* __restrict__ pidx,
    const float* __restrict__ wemb, const float* __restrict__ temb,
    _Float16* __restrict__ whh_f,
    _Float16* __restrict__ wih_f,
    _Float16* __restrict__ wpr_f,
    float* __restrict__ bsum, float* __restrict__ b1cat,
    _Float16* __restrict__ xa)
{
  const int N_whh  = 8 * 40 * 5 * 512;   // 819200
  const int N_wih0 = 2 * 40 * 5 * 512;   // 204800
  const int N_wihr = 6 * 40 * 10 * 512;  // 1228800
  const int N_wpr  = 16 * 10 * 512;      // 81920
  const int N_bs   = 8 * 640;            // 5120
  const int N_emb  = 1536 * 320;         // 491520
  const int total  = N_whh + N_wih0 + N_wihr + N_wpr + N_bs + 256 + N_emb;
  for (int i = blockIdx.x * blockDim.x + threadIdx.x; i < total;
       i += gridDim.x * blockDim.x) {
    int idx = i;
    if (idx < N_whh) {
      int e = idx & 7, lane = (idx >> 3) & 63, r = idx >> 9;
      int kc = r % 5; r /= 5; int nt = r % 40; int ld = r / 40;
      int jrow = (nt >> 2) * 16 + (lane & 15);
      int g = (nt & 3) * 150 + jrow;
      int k = 32 * kc + 16 * (e >> 2) + 4 * (lane >> 4) + (e & 3);
      float v = (jrow < 150 && k < 150) ? Whh[((size_t)ld * 600 + g) * 150 + k] : 0.f;
      v *= ((nt & 3) == 2) ? (2.f * KLOG2E) : (-KLOG2E);
      whh_f[idx] = (_Float16)v;
      continue;
    }
    idx -= N_whh;
    if (idx < N_wih0) {
      int e = idx & 7, lane = (idx >> 3) & 63, r = idx >> 9;
      int kc = r % 5; r /= 5; int nt = r % 40; int dir = r / 40;
      int jrow = (nt >> 2) * 16 + (lane & 15);
      int g = (nt & 3) * 150 + jrow;
      int k = 32 * kc + 16 * (e >> 2) + 4 * (lane >> 4) + (e & 3);
      float v = (jrow < 150 && k < 150) ? Wih0[((size_t)dir * 600 + g) * 150 + k] : 0.f;
      v *= ((nt & 3) == 2) ? (2.f * KLOG2E) : (-KLOG2E);
      wih_f[idx] = (_Float16)v;
      continue;
    }
    idx -= N_wih0;
    if (idx < N_wihr) {
      int e = idx & 7, lane = (idx >> 3) & 63, r = idx >> 9;
      int kc = r % 10; r /= 10; int nt = r % 40; int ld = r / 40;
      int jrow = (nt >> 2) * 16 + (lane & 15);
      int g = (nt & 3) * 150 + jrow;
      int k = 32 * kc + 16 * (e >> 2) + 4 * (lane >> 4) + (e & 3);
      // padded-X remap: x cols [0,150)=dir0 h, [160,310)=dir1 h, rest pad(zero)
      int ks = (k < 150) ? k : ((k >= 160 && k < 310) ? (k - 10) : -1);
      float v = (jrow < 150 && ks >= 0) ? WihR[((size_t)ld * 600 + g) * 300 + ks] : 0.f;
      v *= ((nt & 3) == 2) ? (2.f * KLOG2E) : (-KLOG2E);
      wih_f[N_wih0 + idx] = (_Float16)v;
      continue;
    }
    idx -= N_wihr;
    if (idx < N_wpr) {
      int e = idx & 7, lane = (idx >> 3) & 63, r = idx >> 9;
      int kc = r % 10; int nt = r / 10;
      int ko = 16 * nt + (lane & 15);
      int k = 32 * kc + 16 * (e >> 2) + 4 * (lane >> 4) + (e & 3);
      int ks = (k < 150) ? k : ((k >= 160 && k < 310) ? (k - 10) : -1);
      float v = 0.f;
      if (ks >= 0) {
        if (ko < 100) v = w1m[(size_t)ko * 600 + ks];
        else if (ko < 200) v = w1m[(size_t)(ko - 100) * 600 + 300 + ks];
      }
      wpr_f[idx] = (_Float16)v;
      continue;
    }
    idx -= N_wpr;
    if (idx < N_bs) {
      int ld = idx / 640, gp = idx - 640 * ld;
      int nt = gp >> 4, lrow = gp & 15;
      int jrow = (nt >> 2) * 16 + lrow;
      int g = (nt & 3) * 150 + jrow;
      float v = (jrow < 150) ? bih[ld * 600 + g] + bhh[ld * 600 + g] : 0.f;
      v *= ((nt & 3) == 2) ? (2.f * KLOG2E) : (-KLOG2E);
      bsum[idx] = v;
      continue;
    }
    idx -= N_bs;
    if (idx < 256) {
      b1cat[idx] = (idx < 100) ? b1v[idx] : ((idx < 200) ? b1v[idx - 100] : 0.f);
      continue;
    }
    idx -= 256;
    // embedding gather: idx over [1536][320] (cols >=150 zero)
    {
      int row = idx / 320, j = idx - 320 * row;
      int b = row & 15, t = row >> 4;
      float v = 0.f;
      if (j < 100) v = wemb[(size_t)widx[b * 96 + t] * 100 + j];
      else if (j < 150) v = temb[(size_t)pidx[b * 96 + t] * 50 + (j - 100)];
      xa[idx] = (_Float16)v;
    }
  }
}

// ---------------- pre-GEMM: writes scan-fragment-ordered PRE chunks ----------------
template <int KC>
__global__ __launch_bounds__(512) void pregemm_kernel(
    const _Float16* __restrict__ x_h,
    const _Float16* __restrict__ wih_f,
    const float* __restrict__ bsum_l,
    float* __restrict__ pre)            // [2][96][640][16]
{
  const int t = blockIdx.x, dir = blockIdx.y;
  const int tid = threadIdx.x, wv = tid >> 6, lane = tid & 63;
  const int lrow = lane & 15, lgrp = lane >> 4;
  const _Float16* wf = wih_f + (size_t)dir * 40 * KC * 512;
  float4v acc[5];
#pragma unroll
  for (int tt = 0; tt < 5; ++tt) acc[tt] = (float4v){0.f, 0.f, 0.f, 0.f};
  const size_t arow = ((size_t)t * 16 + lrow) * 320;
#pragma unroll
  for (int kc = 0; kc < KC; ++kc) {
    int co = 32 * kc + 4 * lgrp;
    half8 ah = cat44h(*(const half4*)(x_h + arow + co),
                      *(const half4*)(x_h + arow + co + 16));
#pragma unroll
    for (int tt = 0; tt < 5; ++tt) {
      int nt = 5 * wv + tt;
      const size_t wo = ((size_t)(nt * KC + kc) * 64 + lane) * 8;
      half8 bw = *(const half8*)(wf + wo);
      acc[tt] = mfma16h(ah, bw, acc[tt]);
    }
  }
  float* po = pre + (size_t)(dir * 96 + t) * 10240;
  const float* bs = bsum_l + dir * 640;
#pragma unroll
  for (int tt = 0; tt < 5; ++tt) {
    int nt = 5 * wv + tt;
    float bv = bs[16 * nt + lrow];
    float4v v;
#pragma unroll
    for (int jj = 0; jj < 4; ++jj) v[jj] = acc[tt][jj] + bv;
    int tid_s = (nt >> 2) * 64 + lgrp * 16 + lrow;   // scan-thread owner
    *(float4v*)(po + (size_t)tid_s * 16 + (nt & 3) * 4) = v;
  }
}

// ---------------- sequential LSTM scan: 10 waves, gates thread-local ----------------
// setprio(1) around MFMA cluster staggers wave completion -> MFMA pipe overlaps
// the trans-heavy state phase across waves. State math packed on float2
// (v_pk_*_f32). Counted barrier; padded xo; store-source regs double-buffered.
__global__ __launch_bounds__(640, 1) void scan_kernel(
    const float* __restrict__ pre,                 // [2][96][640][16]
    const _Float16* __restrict__ whh_f,
    _Float16* __restrict__ xo,                     // [1536][320] padded layout
    int layer)
{
  const int dir = blockIdx.x;
  const int tid = threadIdx.x, wv = tid >> 6, lane = tid & 63;
  const int lrow = lane & 15, lgrp = lane >> 4;

  // h in MFMA A-fragment order, row stride 172 (conflict-free ds_read_b128)
  __shared__ __align__(16) _Float16 hb[2][16 * 172];

  for (int i = tid; i < 2 * 16 * 172; i += 640)
    (&hb[0][0])[i] = (_Float16)0.f;

  // Whh fragments resident: 4 gate-quad tiles x 5 kc per wave (40 VGPR)
  const _Float16* b_base = whh_f + (size_t)(layer * 2 + dir) * 40 * 5 * 512;
  half8 Bw[4][5];
#pragma unroll
  for (int tt = 0; tt < 4; ++tt)
#pragma unroll
    for (int kc = 0; kc < 5; ++kc) {
      size_t o = ((size_t)((4 * wv + tt) * 5 + kc) * 64 + lane) * 8;
      Bw[tt][kc] = *(const half8*)(b_base + o);
    }

  float2v cst01 = {0.f, 0.f}, cst23 = {0.f, 0.f};
  const int j = 16 * wv + lrow;          // this thread's cell column
  const int kcj = j >> 5, wj = j & 31;   // h-fragment slot for (b, j)
  const int hoff = kcj * 32 + ((wj >> 2) & 3) * 8 + (wj >> 4) * 4 + (wj & 3);

  const int t0 = dir ? 95 : 0;
  const long pincv = dir ? -2560 : 2560;           // float4v per t step
  const long xinc = dir ? -(16 * 320) : (16 * 320);
  const float4v* pc = (const float4v*)pre + ((size_t)(dir * 96 + t0) * 640 + tid) * 4;
  _Float16* xop = xo + ((size_t)t0 * 16 + 4 * lgrp) * 320 + dir * 160 + j;

  float4v pfA[4], pfB[4];
#pragma unroll
  for (int i = 0; i < 4; ++i) pfA[i] = pc[i];
  pc += pincv;
#pragma unroll
  for (int i = 0; i < 4; ++i) pfB[i] = pc[i];
  pc += pincv;

  // per-parity store-source registers (keep-alive pins liveness ~2 steps)
  _Float16 hsA0 = 0, hsA1 = 0, hsA2 = 0, hsA3 = 0;
  _Float16 hsB0 = 0, hsB1 = 0, hsB2 = 0, hsB3 = 0;
  __syncthreads();

#define GATE_PAIR(PF, J0, J1, CST, HVO)                                   \
  {                                                                       \
    float2v zi = {__builtin_amdgcn_exp2f(PF[0][J0]),                      \
                  __builtin_amdgcn_exp2f(PF[0][J1])};                     \
    float2v zf = {__builtin_amdgcn_exp2f(PF[1][J0]),                      \
                  __builtin_amdgcn_exp2f(PF[1][J1])};                     \
    float2v zg = {__builtin_amdgcn_exp2f(PF[2][J0]),                      \
                  __builtin_amdgcn_exp2f(PF[2][J1])};                     \
    float2v zo = {__builtin_amdgcn_exp2f(PF[3][J0]),                      \
                  __builtin_amdgcn_exp2f(PF[3][J1])};                     \
    float2v tq = (1.f + zi) * (zg + 1.f);                                 \
    float2v fq = 1.f + zf;                                                \
    float2v Dq = tq * fq;                                                 \
    float2v Nq = CST * tq + (zg - 1.f) * fq;                              \
    float rP = __builtin_amdgcn_rcpf(Dq[0] * Dq[1]);                      \
    float2v Dsw = __builtin_shufflevector(Dq, Dq, 1, 0);                  \
    float2v cv = Nq * rP * Dsw;                                           \
    CST = cv;                                                             \
    float2v arg = (2.f * KLOG2E) * cv;                                    \
    float2v zc = {__builtin_amdgcn_exp2f(arg[0]),                         \
                  __builtin_amdgcn_exp2f(arg[1])};                        \
    float2v Eq = (1.f + zo) * (zc + 1.f);                                 \
    float rE = __builtin_amdgcn_rcpf(Eq[0] * Eq[1]);                      \
    float2v Esw = __builtin_shufflevector(Eq, Eq, 1, 0);                  \
    HVO = (zc - 1.f) * rE * Esw;                                          \
  }

#define SCAN_STEP(PF, H0, H1, H2, H3, O0, O1, O2, O3, HIN, HOUT)          \
  {                                                                       \
    asm volatile("" :: "v"(O0), "v"(O1), "v"(O2), "v"(O3));               \
    __builtin_amdgcn_s_setprio(1);                                        \
    _Pragma("unroll")                                                     \
    for (int kc = 0; kc < 5; ++kc) {                                      \
      const int ao = lrow * 172 + kc * 32 + lgrp * 8;                     \
      half8 ah = *(const half8*)((HIN) + ao);                             \
      _Pragma("unroll")                                                   \
      for (int tt = 0; tt < 4; ++tt)                                      \
        PF[tt] = mfma16h(ah, Bw[tt][kc], PF[tt]);                         \
    }                                                                     \
    __builtin_amdgcn_s_setprio(0);                                        \
    float2v hv01, hv23;                                                   \
    GATE_PAIR(PF, 0, 1, cst01, hv01)                                      \
    GATE_PAIR(PF, 2, 3, cst23, hv23)                                      \
    H0 = (_Float16)hv01[0];                                               \
    H1 = (_Float16)hv01[1];                                               \
    H2 = (_Float16)hv23[0];                                               \
    H3 = (_Float16)hv23[1];                                               \
    (HOUT)[(4 * lgrp + 0) * 172 + hoff] = H0;                             \
    (HOUT)[(4 * lgrp + 1) * 172 + hoff] = H1;                             \
    (HOUT)[(4 * lgrp + 2) * 172 + hoff] = H2;                             \
    (HOUT)[(4 * lgrp + 3) * 172 + hoff] = H3;                             \
    xop[0 * 320] = H0; xop[1 * 320] = H1;                                 \
    xop[2 * 320] = H2; xop[3 * 320] = H3;                                 \
    _Pragma("unroll")                                                     \
    for (int i = 0; i < 4; ++i) PF[i] = pc[i];                            \
    pc += pincv;                                                          \
    xop += xinc;                                                          \
    asm volatile("s_waitcnt lgkmcnt(0)" ::: "memory");                    \
    __builtin_amdgcn_s_barrier();                                         \
  }

#pragma unroll 1
  for (int s2 = 0; s2 < 48; ++s2) {
    SCAN_STEP(pfA, hsA0, hsA1, hsA2, hsA3, hsB0, hsB1, hsB2, hsB3, hb[0], hb[1]);
    SCAN_STEP(pfB, hsB0, hsB1, hsB2, hsB3, hsA0, hsA1, hsA2, hsA3, hb[1], hb[0]);
  }
#undef SCAN_STEP
#undef GATE_PAIR
}

// ---------------- projection (poly fused in via LDS stage) ----------------
// AD[row][0:100]=A+b1, [100:200]=D
__global__ __launch_bounds__(512) void proj_kernel(
    const _Float16* __restrict__ xi,      // [1536][320] layer-3 output (padded)
    const _Float16* __restrict__ wpr_f,
    const float* __restrict__ b1cat,
    const float* __restrict__ w1, const float* __restrict__ w2,
    const float* __restrict__ w3, const float* __restrict__ w4,
    float* __restrict__ AD)   // [1536][256]
{
  const int t = blockIdx.x;
  const int tid = threadIdx.x, wv = tid >> 6, lane = tid & 63;
  const int lrow = lane & 15, lgrp = lane >> 4;
  __shared__ __align__(16) _Float16 ph[16 * 328];  // stride 328: 2-way conflicts only
  __shared__ __align__(16) _Float16 pl[16 * 328];
  {
    float c1 = w1[0], c2 = w2[0], c3 = w3[0], c4 = w4[0];
    for (int e = tid; e < 16 * 320; e += 512) {
      int row = e / 320, col = e - 320 * row;
      float x = (float)xi[(size_t)t * 5120 + e];
      float p = x * (c1 + x * (c2 + x * (c3 + x * c4)));
      _Float16 h, l; split_f16(p, h, l);
      ph[row * 328 + col] = h; pl[row * 328 + col] = l;
    }
  }
  __syncthreads();
  float4v acc[2] = {{0.f, 0.f, 0.f, 0.f}, {0.f, 0.f, 0.f, 0.f}};
#pragma unroll
  for (int kc = 0; kc < 10; ++kc) {
    int co = lrow * 328 + 32 * kc + 4 * lgrp;
    half8 ah = cat44h(*(const half4*)(ph + co), *(const half4*)(ph + co + 16));
    half8 al = cat44h(*(const half4*)(pl + co), *(const half4*)(pl + co + 16));
#pragma unroll
    for (int tt = 0; tt < 2; ++tt) {
      int nt = 2 * wv + tt;
      size_t wo = ((size_t)(nt * 10 + kc) * 64 + lane) * 8;
      half8 bw = *(const half8*)(wpr_f + wo);
      acc[tt] = mfma16h(ah, bw, acc[tt]);
      acc[tt] = mfma16h(al, bw, acc[tt]);
    }
  }
#pragma unroll
  for (int tt = 0; tt < 2; ++tt) {
    int ko = 16 * (2 * wv + tt) + lrow;
    float bv = b1cat[ko];
#pragma unroll
    for (int jj = 0; jj < 4; ++jj)
      AD[((size_t)t * 16 + 4 * lgrp + jj) * 256 + ko] = acc[tt][jj] + bv;
  }
}

// ---------------- combine: out[lh][b][ld] = b2 + sum_k w2[k]*tanh(A+D) ----------------
__global__ __launch_bounds__(768) void combine_kernel(
    const float* __restrict__ AD, const float* __restrict__ w2v,
    const float* __restrict__ b2v, float* __restrict__ out)
{
  const int bb = blockIdx.x & 15, lt = blockIdx.x >> 4;
  const int tid = threadIdx.x;
  __shared__ float Dl[100 * 97];  // [k][ld], stride 97
  __shared__ float Al[100 * 9];   // [k][lh], stride 9
  __shared__ float w2s[100];
  for (int i = tid; i < 96 * 32; i += 768) {
    int ld = i >> 5, f4 = i & 31;
    if (f4 < 25) {
      float4v v = *(const float4v*)(AD + ((size_t)ld * 16 + bb) * 256 + 100 + 4 * f4);
      int k0 = 4 * f4;
      Dl[(k0 + 0) * 97 + ld] = v[0];
      Dl[(k0 + 1) * 97 + ld] = v[1];
      Dl[(k0 + 2) * 97 + ld] = v[2];
      Dl[(k0 + 3) * 97 + ld] = v[3];
    }
  }
  for (int i = tid; i < 8 * 32; i += 768) {
    int lh = i >> 5, f4 = i & 31;
    if (f4 < 25) {
      int lseq = lt * 8 + lh;
      float4v v = *(const float4v*)(AD + ((size_t)lseq * 16 + bb) * 256 + 4 * f4);
      int k0 = 4 * f4;
      Al[(k0 + 0) * 9 + lh] = v[0];
      Al[(k0 + 1) * 9 + lh] = v[1];
      Al[(k0 + 2) * 9 + lh] = v[2];
      Al[(k0 + 3) * 9 + lh] = v[3];
    }
  }
  if (tid < 100) w2s[tid] = w2v[tid];
  __syncthreads();
  int lh = tid / 96, ld = tid - 96 * lh;
  float s = 0.f;
#pragma unroll 4
  for (int k = 0; k < 100; ++k) {
    float x = Al[k * 9 + lh] + Dl[k * 97 + ld];
    s += w2s[k] * fast_tanh(x);
  }
  out[((size_t)(lt * 8 + lh) * 16 + bb) * 96 + ld] = s + b2v[0];
}

// ---------------- host ----------------
extern "C" void kernel_launch(void* const* d_in, const int* in_sizes, int n_in,
                              void* d_out, int out_size, void* d_ws, size_t ws_size,
                              hipStream_t stream)
{
  const int*   widx = (const int*)d_in[0];
  const int*   pidx = (const int*)d_in[1];
  const float* wemb = (const float*)d_in[3];
  const float* temb = (const float*)d_in[4];
  const float* Wih0 = (const float*)d_in[5];
  const float* WihR = (const float*)d_in[6];
  const float* Whh  = (const float*)d_in[7];
  const float* bih  = (const float*)d_in[8];
  const float* bhh  = (const float*)d_in[9];
  const float* w1   = (const float*)d_in[10];
  const float* w2   = (const float*)d_in[11];
  const float* w3   = (const float*)d_in[12];
  const float* w4   = (const float*)d_in[13];
  const float* w1m  = (const float*)d_in[14];
  const float* b1v  = (const float*)d_in[15];
  const float* w2m  = (const float*)d_in[16];
  const float* b2v  = (const float*)d_in[17];
  float* out = (float*)d_out;

  char* ws = (char*)d_ws;
  size_t off = 0;
  auto alloc = [&](size_t bytes) -> char* {
    char* p = ws + off;
    off = (off + bytes + 255) & ~(size_t)255;
    return p;
  };
  _Float16* WHH_F = (_Float16*)alloc(819200ull * 2);
  _Float16* WIH_F = (_Float16*)alloc(1433600ull * 2);
  _Float16* WPR_F = (_Float16*)alloc(81920ull * 2);
  float* BSUM = (float*)alloc(5120ull * 4);
  float* B1C  = (float*)alloc(256ull * 4);
  _Float16* XA = (_Float16*)alloc(491520ull * 2);
  _Float16* XB = (_Float16*)alloc(491520ull * 2);
  float* PRE = (float*)alloc(1966080ull * 4);
  float* AD  = (float*)alloc(1536ull * 256 * 4);

  prep_kernel<<<512, 256, 0, stream>>>(Wih0, WihR, Whh, bih, bhh, w1m, b1v,
      widx, pidx, wemb, temb,
      WHH_F, WIH_F, WPR_F, BSUM, B1C, XA);

  for (int layer = 0; layer < 4; ++layer) {
    const _Float16* xin = (layer & 1) ? XB : XA;
    _Float16* xout = (layer & 1) ? XA : XB;
    const float* bsl = BSUM + layer * 2 * 640;
    if (layer == 0) {
      pregemm_kernel<5><<<dim3(96, 2), 512, 0, stream>>>(xin, WIH_F, bsl, PRE);
    } else {
      size_t wo = 204800ull + (size_t)(layer - 1) * 409600ull;
      pregemm_kernel<10><<<dim3(96, 2), 512, 0, stream>>>(xin, WIH_F + wo, bsl, PRE);
    }
    scan_kernel<<<2, 640, 0, stream>>>(PRE, WHH_F, xout, layer);
  }
  // layer-3 output sits in XA; proj (poly fused) -> AD; combine -> out
  proj_kernel<<<96, 512, 0, stream>>>(XA, WPR_F, B1C, w1, w2, w3, w4, AD);
  combine_kernel<<<192, 768, 0, stream>>>(AD, w2m, b2v, out);
}